// Round 1
// baseline (1700.459 us; speedup 1.0000x reference)
//
#include <hip/hip_runtime.h>

#define DIN 128
#define DH  256
#define DOUT 128
#define BN_EPS 1e-5f

// ---------------- GEMM: C[M,N] = A[M,K] @ W[K,N]  (optionally += ) ----------------
// BM=BN=64, BK=16, 256 threads, 4x4 micro-tile per thread.
__global__ __launch_bounds__(256) void gemm_kernel(
    const float* __restrict__ A, const float* __restrict__ W, float* __restrict__ C,
    int M, int N, int K, int accumulate)
{
    const int BM = 64, BN = 64, BK = 16;
    __shared__ float As[BK][BM + 4];   // transposed A tile, padded
    __shared__ float Bs[BK][BN + 4];

    int tid = threadIdx.x;
    int ty = tid >> 4;        // 0..15 -> row group
    int tx = tid & 15;        // 0..15 -> col group
    int rowBase = blockIdx.x * BM;
    int colBase = blockIdx.y * BN;

    int arow = tid >> 2;          // 0..63
    int acol = (tid & 3) * 4;     // 0,4,8,12
    int wrow = tid >> 4;          // 0..15
    int wcol = (tid & 15) * 4;    // 0..60

    float acc[4][4] = {};

    for (int k0 = 0; k0 < K; k0 += BK) {
        // A tile (64 x 16), store transposed
        {
            int r = rowBase + arow;
            float4 v = make_float4(0.f, 0.f, 0.f, 0.f);
            if (r < M) v = *(const float4*)&A[(long)r * K + k0 + acol];
            As[acol + 0][arow] = v.x;
            As[acol + 1][arow] = v.y;
            As[acol + 2][arow] = v.z;
            As[acol + 3][arow] = v.w;
            // W tile (16 x 64)
            float4 w = *(const float4*)&W[(long)(k0 + wrow) * N + colBase + wcol];
            *(float4*)&Bs[wrow][wcol] = w;
        }
        __syncthreads();
        #pragma unroll
        for (int kk = 0; kk < BK; kk++) {
            float4 a4 = *(const float4*)&As[kk][ty * 4];
            float4 b4 = *(const float4*)&Bs[kk][tx * 4];
            float av[4] = {a4.x, a4.y, a4.z, a4.w};
            float bv[4] = {b4.x, b4.y, b4.z, b4.w};
            #pragma unroll
            for (int i = 0; i < 4; i++)
                #pragma unroll
                for (int j = 0; j < 4; j++)
                    acc[i][j] += av[i] * bv[j];
        }
        __syncthreads();
    }

    #pragma unroll
    for (int i = 0; i < 4; i++) {
        int r = rowBase + ty * 4 + i;
        if (r < M) {
            float* cp = &C[(long)r * N + colBase + tx * 4];
            float4 out;
            if (accumulate) {
                float4 old = *(const float4*)cp;
                out = make_float4(old.x + acc[i][0], old.y + acc[i][1],
                                  old.z + acc[i][2], old.w + acc[i][3]);
            } else {
                out = make_float4(acc[i][0], acc[i][1], acc[i][2], acc[i][3]);
            }
            *(float4*)cp = out;
        }
    }
}

// ---------------- column stats: sums / sumsq per column ----------------
__global__ __launch_bounds__(256) void colstats_kernel(
    const float* __restrict__ X, float* __restrict__ sums, float* __restrict__ sqs,
    int total, int N)
{
    __shared__ float ls[DH];
    __shared__ float lq[DH];
    for (int c = threadIdx.x; c < N; c += blockDim.x) { ls[c] = 0.f; lq[c] = 0.f; }
    __syncthreads();
    int stride = gridDim.x * blockDim.x;
    for (int i = blockIdx.x * blockDim.x + threadIdx.x; i < total; i += stride) {
        float x = X[i];
        int c = i & (N - 1);
        atomicAdd(&ls[c], x);
        atomicAdd(&lq[c], x * x);
    }
    __syncthreads();
    for (int c = threadIdx.x; c < N; c += blockDim.x) {
        atomicAdd(&sums[c], ls[c]);
        atomicAdd(&sqs[c], lq[c]);
    }
}

// ---------------- finalize BN params: scale/shift ----------------
__global__ void bnparam_kernel(const float* __restrict__ sums, const float* __restrict__ sqs,
                               const float* __restrict__ gamma, const float* __restrict__ beta,
                               float* __restrict__ scale, float* __restrict__ shift,
                               int N, float invM)
{
    int c = blockIdx.x * blockDim.x + threadIdx.x;
    if (c < N) {
        float mean = sums[c] * invM;
        float var = sqs[c] * invM - mean * mean;
        float sc = gamma[c] * rsqrtf(var + BN_EPS);
        scale[c] = sc;
        shift[c] = beta[c] - mean * sc;
    }
}

// ---------------- BN transform + activation (in place) ----------------
// negSlope = 0 -> ReLU; 0.01 -> LeakyReLU
__global__ __launch_bounds__(256) void bnact_kernel(
    float* __restrict__ X, const float* __restrict__ scale, const float* __restrict__ shift,
    int total, int N, float negSlope)
{
    int stride = gridDim.x * blockDim.x;
    for (int i = blockIdx.x * blockDim.x + threadIdx.x; i < total; i += stride) {
        int c = i & (N - 1);
        float v = X[i] * scale[c] + shift[c];
        X[i] = (v > 0.f) ? v : v * negSlope;
    }
}

// ---------------- degree histogram ----------------
__global__ void deg_kernel(const int* __restrict__ dst, float* __restrict__ deg, int E)
{
    int i = blockIdx.x * blockDim.x + threadIdx.x;
    if (i < E) atomicAdd(&deg[dst[i]], 1.0f);
}

// ---------------- scatter-add: agg[dst] += X[src] ----------------
__global__ __launch_bounds__(256) void scatter_kernel(
    const float* __restrict__ X, const int* __restrict__ src, const int* __restrict__ dst,
    float* __restrict__ agg, int E, int D, int logD)
{
    int total = E * D;
    int stride = gridDim.x * blockDim.x;
    for (int i = blockIdx.x * blockDim.x + threadIdx.x; i < total; i += stride) {
        int e = i >> logD;
        int f = i & (D - 1);
        atomicAdd(&agg[(long)dst[e] * D + f], X[(long)src[e] * D + f]);
    }
}

// ---------------- agg /= max(deg,1) ----------------
__global__ __launch_bounds__(256) void norm_kernel(
    float* __restrict__ agg, const float* __restrict__ deg, int total, int logD)
{
    int stride = gridDim.x * blockDim.x;
    for (int i = blockIdx.x * blockDim.x + threadIdx.x; i < total; i += stride) {
        int r = i >> logD;
        float d = deg[r];
        agg[i] = agg[i] / fmaxf(d, 1.0f);
    }
}

extern "C" void kernel_launch(void* const* d_in, const int* in_sizes, int n_in,
                              void* d_out, int out_size, void* d_ws, size_t ws_size,
                              hipStream_t stream)
{
    const float* nodes = (const float*)d_in[0];
    const int*   src   = (const int*)d_in[1];
    const int*   dst   = (const int*)d_in[2];
    const float* Wf1   = (const float*)d_in[3];
    const float* gf1   = (const float*)d_in[5];
    const float* bef1  = (const float*)d_in[6];
    const float* Wf2   = (const float*)d_in[7];
    const float* gf2   = (const float*)d_in[9];
    const float* bef2  = (const float*)d_in[10];
    const float* Ws1   = (const float*)d_in[11];
    const float* Wn1   = (const float*)d_in[12];
    const float* gs1   = (const float*)d_in[14];
    const float* bs1   = (const float*)d_in[15];
    const float* Ws2   = (const float*)d_in[16];
    const float* Wn2   = (const float*)d_in[17];
    const float* gs2   = (const float*)d_in[19];
    const float* bs2   = (const float*)d_in[20];
    // note: all pre-BN biases (bf1,bf2,b1,b2) cancel under BatchNorm -> skipped

    int nN = in_sizes[0] / DIN;   // 50000
    int nE = in_sizes[1];         // 600000
    float* out = (float*)d_out;

    float* ws   = (float*)d_ws;
    float* buf1 = ws;                              // nN*DH   (X1/h_a, then H1/h1)
    float* buf2 = buf1 + (size_t)nN * DH;          // nN*DIN  (X2/h)
    float* buf3 = buf2 + (size_t)nN * DIN;         // nN*DIN  (agg1)
    float* buf5 = buf2;                            // nN*DH   overlay (agg2), h/agg1 dead by then
    float* deg  = buf3 + (size_t)nN * DIN;         // nN
    float* sums = deg + nN;                        // DH
    float* sqs  = sums + DH;                       // DH
    float* scale= sqs + DH;                        // DH
    float* shift= scale + DH;                      // DH

    dim3 blk(256);
    auto cdiv = [](int a, int b) { return (a + b - 1) / b; };

    // ---- FF layer 1: buf1 = nodes @ Wf1 ; BN + ReLU ----
    gemm_kernel<<<dim3(cdiv(nN, 64), DH / 64), blk, 0, stream>>>(nodes, Wf1, buf1, nN, DH, DIN, 0);
    hipMemsetAsync(sums, 0, 2 * DH * sizeof(float), stream);
    colstats_kernel<<<dim3(1024), blk, 0, stream>>>(buf1, sums, sqs, nN * DH, DH);
    bnparam_kernel<<<dim3(1), blk, 0, stream>>>(sums, sqs, gf1, bef1, scale, shift, DH, 1.0f / nN);
    bnact_kernel<<<dim3(2048), blk, 0, stream>>>(buf1, scale, shift, nN * DH, DH, 0.0f);

    // ---- FF layer 2: buf2 = buf1 @ Wf2 ; BN + ReLU ----
    gemm_kernel<<<dim3(cdiv(nN, 64), DIN / 64), blk, 0, stream>>>(buf1, Wf2, buf2, nN, DIN, DH, 0);
    hipMemsetAsync(sums, 0, 2 * DH * sizeof(float), stream);
    colstats_kernel<<<dim3(1024), blk, 0, stream>>>(buf2, sums, sqs, nN * DIN, DIN);
    bnparam_kernel<<<dim3(1), blk, 0, stream>>>(sums, sqs, gf2, bef2, scale, shift, DIN, 1.0f / nN);
    bnact_kernel<<<dim3(2048), blk, 0, stream>>>(buf2, scale, shift, nN * DIN, DIN, 0.0f);

    // ---- SAGE layer 1 aggregation: agg1 = mean_{src->dst}(h) ----
    hipMemsetAsync(deg, 0, (size_t)nN * sizeof(float), stream);
    hipMemsetAsync(buf3, 0, (size_t)nN * DIN * sizeof(float), stream);
    deg_kernel<<<dim3(cdiv(nE, 256)), blk, 0, stream>>>(dst, deg, nE);
    scatter_kernel<<<dim3(4096), blk, 0, stream>>>(buf2, src, dst, buf3, nE, DIN, 7);
    norm_kernel<<<dim3(2048), blk, 0, stream>>>(buf3, deg, nN * DIN, 7);

    // ---- SAGE layer 1: H1 = h@Ws1 + agg1@Wn1 ; BN + LeakyReLU -> buf1 ----
    gemm_kernel<<<dim3(cdiv(nN, 64), DH / 64), blk, 0, stream>>>(buf2, Ws1, buf1, nN, DH, DIN, 0);
    gemm_kernel<<<dim3(cdiv(nN, 64), DH / 64), blk, 0, stream>>>(buf3, Wn1, buf1, nN, DH, DIN, 1);
    hipMemsetAsync(sums, 0, 2 * DH * sizeof(float), stream);
    colstats_kernel<<<dim3(1024), blk, 0, stream>>>(buf1, sums, sqs, nN * DH, DH);
    bnparam_kernel<<<dim3(1), blk, 0, stream>>>(sums, sqs, gs1, bs1, scale, shift, DH, 1.0f / nN);
    bnact_kernel<<<dim3(2048), blk, 0, stream>>>(buf1, scale, shift, nN * DH, DH, 0.01f);

    // ---- SAGE layer 2 aggregation: agg2 = mean_{src->dst}(h1) -> buf5 (overlay) ----
    hipMemsetAsync(buf5, 0, (size_t)nN * DH * sizeof(float), stream);
    scatter_kernel<<<dim3(8192), blk, 0, stream>>>(buf1, src, dst, buf5, nE, DH, 8);
    norm_kernel<<<dim3(2048), blk, 0, stream>>>(buf5, deg, nN * DH, 8);

    // ---- SAGE layer 2: H2 = h1@Ws2 + agg2@Wn2 ; BN + LeakyReLU -> out ----
    gemm_kernel<<<dim3(cdiv(nN, 64), DOUT / 64), blk, 0, stream>>>(buf1, Ws2, out, nN, DOUT, DH, 0);
    gemm_kernel<<<dim3(cdiv(nN, 64), DOUT / 64), blk, 0, stream>>>(buf5, Wn2, out, nN, DOUT, DH, 1);
    hipMemsetAsync(sums, 0, 2 * DH * sizeof(float), stream);
    colstats_kernel<<<dim3(1024), blk, 0, stream>>>(out, sums, sqs, nN * DOUT, DOUT);
    bnparam_kernel<<<dim3(1), blk, 0, stream>>>(sums, sqs, gs2, bs2, scale, shift, DOUT, 1.0f / nN);
    bnact_kernel<<<dim3(2048), blk, 0, stream>>>(out, scale, shift, nN * DOUT, DOUT, 0.01f);
}

// Round 2
// 1077.019 us; speedup vs baseline: 1.5789x; 1.5789x over previous
//
#include <hip/hip_runtime.h>

#define DIN 128
#define DH  256
#define DOUT 128
#define BN_EPS 1e-5f

// ---------------- GEMM: C[M,N] = A[M,K] @ W[K,N]  (optionally += ) ----------------
__global__ __launch_bounds__(256) void gemm_kernel(
    const float* __restrict__ A, const float* __restrict__ W, float* __restrict__ C,
    int M, int N, int K, int accumulate)
{
    const int BM = 64, BN = 64, BK = 16;
    __shared__ float As[BK][BM + 4];
    __shared__ float Bs[BK][BN + 4];

    int tid = threadIdx.x;
    int ty = tid >> 4;
    int tx = tid & 15;
    int rowBase = blockIdx.x * BM;
    int colBase = blockIdx.y * BN;

    int arow = tid >> 2;
    int acol = (tid & 3) * 4;
    int wrow = tid >> 4;
    int wcol = (tid & 15) * 4;

    float acc[4][4] = {};

    for (int k0 = 0; k0 < K; k0 += BK) {
        {
            int r = rowBase + arow;
            float4 v = make_float4(0.f, 0.f, 0.f, 0.f);
            if (r < M) v = *(const float4*)&A[(long)r * K + k0 + acol];
            As[acol + 0][arow] = v.x;
            As[acol + 1][arow] = v.y;
            As[acol + 2][arow] = v.z;
            As[acol + 3][arow] = v.w;
            float4 w = *(const float4*)&W[(long)(k0 + wrow) * N + colBase + wcol];
            *(float4*)&Bs[wrow][wcol] = w;
        }
        __syncthreads();
        #pragma unroll
        for (int kk = 0; kk < BK; kk++) {
            float4 a4 = *(const float4*)&As[kk][ty * 4];
            float4 b4 = *(const float4*)&Bs[kk][tx * 4];
            float av[4] = {a4.x, a4.y, a4.z, a4.w};
            float bv[4] = {b4.x, b4.y, b4.z, b4.w};
            #pragma unroll
            for (int i = 0; i < 4; i++)
                #pragma unroll
                for (int j = 0; j < 4; j++)
                    acc[i][j] += av[i] * bv[j];
        }
        __syncthreads();
    }

    #pragma unroll
    for (int i = 0; i < 4; i++) {
        int r = rowBase + ty * 4 + i;
        if (r < M) {
            float* cp = &C[(long)r * N + colBase + tx * 4];
            float4 out;
            if (accumulate) {
                float4 old = *(const float4*)cp;
                out = make_float4(old.x + acc[i][0], old.y + acc[i][1],
                                  old.z + acc[i][2], old.w + acc[i][3]);
            } else {
                out = make_float4(acc[i][0], acc[i][1], acc[i][2], acc[i][3]);
            }
            *(float4*)cp = out;
        }
    }
}

// ---------------- column stats ----------------
__global__ __launch_bounds__(256) void colstats_kernel(
    const float* __restrict__ X, float* __restrict__ sums, float* __restrict__ sqs,
    int total, int N)
{
    __shared__ float ls[DH];
    __shared__ float lq[DH];
    for (int c = threadIdx.x; c < N; c += blockDim.x) { ls[c] = 0.f; lq[c] = 0.f; }
    __syncthreads();
    int stride = gridDim.x * blockDim.x;
    for (int i = blockIdx.x * blockDim.x + threadIdx.x; i < total; i += stride) {
        float x = X[i];
        int c = i & (N - 1);
        atomicAdd(&ls[c], x);
        atomicAdd(&lq[c], x * x);
    }
    __syncthreads();
    for (int c = threadIdx.x; c < N; c += blockDim.x) {
        atomicAdd(&sums[c], ls[c]);
        atomicAdd(&sqs[c], lq[c]);
    }
}

__global__ void bnparam_kernel(const float* __restrict__ sums, const float* __restrict__ sqs,
                               const float* __restrict__ gamma, const float* __restrict__ beta,
                               float* __restrict__ scale, float* __restrict__ shift,
                               int N, float invM)
{
    int c = blockIdx.x * blockDim.x + threadIdx.x;
    if (c < N) {
        float mean = sums[c] * invM;
        float var = sqs[c] * invM - mean * mean;
        float sc = gamma[c] * rsqrtf(var + BN_EPS);
        scale[c] = sc;
        shift[c] = beta[c] - mean * sc;
    }
}

__global__ __launch_bounds__(256) void bnact_kernel(
    float* __restrict__ X, const float* __restrict__ scale, const float* __restrict__ shift,
    int total, int N, float negSlope)
{
    int stride = gridDim.x * blockDim.x;
    for (int i = blockIdx.x * blockDim.x + threadIdx.x; i < total; i += stride) {
        int c = i & (N - 1);
        float v = X[i] * scale[c] + shift[c];
        X[i] = (v > 0.f) ? v : v * negSlope;
    }
}

// ---------------- CSR build ----------------
__global__ void degcount_kernel(const int* __restrict__ dst, int* __restrict__ degi, int E)
{
    int i = blockIdx.x * blockDim.x + threadIdx.x;
    if (i < E) atomicAdd(&degi[dst[i]], 1);
}

__global__ __launch_bounds__(256) void scan_block_sums(const int* __restrict__ degi,
                                                       int* __restrict__ partial, int n)
{
    __shared__ int s[256];
    int i = blockIdx.x * 256 + threadIdx.x;
    s[threadIdx.x] = (i < n) ? degi[i] : 0;
    __syncthreads();
    for (int off = 128; off > 0; off >>= 1) {
        if (threadIdx.x < off) s[threadIdx.x] += s[threadIdx.x + off];
        __syncthreads();
    }
    if (threadIdx.x == 0) partial[blockIdx.x] = s[0];
}

__global__ __launch_bounds__(256) void scan_partials(int* __restrict__ partial, int nb)
{
    __shared__ int s[256];
    int v = (threadIdx.x < nb) ? partial[threadIdx.x] : 0;
    s[threadIdx.x] = v;
    __syncthreads();
    for (int off = 1; off < 256; off <<= 1) {
        int t = (threadIdx.x >= off) ? s[threadIdx.x - off] : 0;
        __syncthreads();
        s[threadIdx.x] += t;
        __syncthreads();
    }
    if (threadIdx.x < nb) partial[threadIdx.x] = s[threadIdx.x] - v;  // exclusive
}

__global__ __launch_bounds__(256) void scan_final(const int* __restrict__ degi,
                                                  const int* __restrict__ partial,
                                                  int* __restrict__ rowstart, int n)
{
    __shared__ int s[256];
    int i = blockIdx.x * 256 + threadIdx.x;
    int v = (i < n) ? degi[i] : 0;
    s[threadIdx.x] = v;
    __syncthreads();
    for (int off = 1; off < 256; off <<= 1) {
        int t = (threadIdx.x >= off) ? s[threadIdx.x - off] : 0;
        __syncthreads();
        s[threadIdx.x] += t;
        __syncthreads();
    }
    if (i < n) rowstart[i] = partial[blockIdx.x] + s[threadIdx.x] - v;  // exclusive
}

__global__ void fillcsr_kernel(const int* __restrict__ src, const int* __restrict__ dst,
                               const int* __restrict__ rowstart, int* __restrict__ cursor,
                               int* __restrict__ csr, int E)
{
    int i = blockIdx.x * blockDim.x + threadIdx.x;
    if (i < E) {
        int d = dst[i];
        int p = atomicAdd(&cursor[d], 1);
        csr[rowstart[d] + p] = src[i];
    }
}

// ---------------- gather mean-aggregation: one wave per dst node, D=128 ----------------
__global__ __launch_bounds__(256) void gather128_kernel(
    const float* __restrict__ X, const int* __restrict__ rowstart,
    const int* __restrict__ degi, const int* __restrict__ csr,
    float* __restrict__ O, int nN)
{
    int wave = (blockIdx.x * blockDim.x + threadIdx.x) >> 6;
    int lane = threadIdx.x & 63;
    if (wave >= nN) return;
    int start = rowstart[wave];
    int d = degi[wave];
    float2 acc = make_float2(0.f, 0.f);
    const int col = lane * 2;
    for (int j = 0; j < d; j++) {
        int s = csr[start + j];
        float2 v = *(const float2*)&X[(long)s * 128 + col];
        acc.x += v.x;
        acc.y += v.y;
    }
    float inv = 1.0f / fmaxf((float)d, 1.0f);
    *(float2*)&O[(long)wave * 128 + col] = make_float2(acc.x * inv, acc.y * inv);
}

extern "C" void kernel_launch(void* const* d_in, const int* in_sizes, int n_in,
                              void* d_out, int out_size, void* d_ws, size_t ws_size,
                              hipStream_t stream)
{
    const float* nodes = (const float*)d_in[0];
    const int*   src   = (const int*)d_in[1];
    const int*   dst   = (const int*)d_in[2];
    const float* Wf1   = (const float*)d_in[3];
    const float* gf1   = (const float*)d_in[5];
    const float* bef1  = (const float*)d_in[6];
    const float* Wf2   = (const float*)d_in[7];
    const float* gf2   = (const float*)d_in[9];
    const float* bef2  = (const float*)d_in[10];
    const float* Ws1   = (const float*)d_in[11];
    const float* Wn1   = (const float*)d_in[12];
    const float* gs1   = (const float*)d_in[14];
    const float* bs1   = (const float*)d_in[15];
    const float* Ws2   = (const float*)d_in[16];
    const float* Wn2   = (const float*)d_in[17];
    const float* gs2   = (const float*)d_in[19];
    const float* bs2   = (const float*)d_in[20];
    // pre-BN biases (bf1,bf2,b1,b2) cancel under BatchNorm -> skipped

    int nN = in_sizes[0] / DIN;   // 50000
    int nE = in_sizes[1];         // 600000
    float* out = (float*)d_out;

    // workspace layout
    float* A    = (float*)d_ws;                    // nN*DH : X1, later H1/h1
    float* B    = A + (size_t)nN * DH;             // nN*DIN: h, later y2
    float* C    = B + (size_t)nN * DIN;            // nN*DIN: agg1
    float* sums = C + (size_t)nN * DIN;            // DH
    float* sqs  = sums + DH;
    float* scale= sqs + DH;
    float* shift= scale + DH;
    int* degi     = (int*)(shift + DH);            // nN
    int* rowstart = degi + nN;                     // nN
    int* cursor   = rowstart + nN;                 // nN
    int* partial  = cursor + nN;                   // 256
    int* csr      = partial + 256;                 // nE

    dim3 blk(256);
    auto cdiv = [](int a, int b) { return (a + b - 1) / b; };
    int nScanBlocks = cdiv(nN, 256);  // 196

    // ---- CSR build (once, reused by both layers) ----
    hipMemsetAsync(degi, 0, (size_t)nN * sizeof(int), stream);
    hipMemsetAsync(cursor, 0, (size_t)nN * sizeof(int), stream);
    degcount_kernel<<<dim3(cdiv(nE, 256)), blk, 0, stream>>>(dst, degi, nE);
    scan_block_sums<<<dim3(nScanBlocks), blk, 0, stream>>>(degi, partial, nN);
    scan_partials<<<dim3(1), blk, 0, stream>>>(partial, nScanBlocks);
    scan_final<<<dim3(nScanBlocks), blk, 0, stream>>>(degi, partial, rowstart, nN);
    fillcsr_kernel<<<dim3(cdiv(nE, 256)), blk, 0, stream>>>(src, dst, rowstart, cursor, csr, nE);

    // ---- FF layer 1: A = nodes @ Wf1 ; BN + ReLU ----
    gemm_kernel<<<dim3(cdiv(nN, 64), DH / 64), blk, 0, stream>>>(nodes, Wf1, A, nN, DH, DIN, 0);
    hipMemsetAsync(sums, 0, 2 * DH * sizeof(float), stream);
    colstats_kernel<<<dim3(1024), blk, 0, stream>>>(A, sums, sqs, nN * DH, DH);
    bnparam_kernel<<<dim3(1), blk, 0, stream>>>(sums, sqs, gf1, bef1, scale, shift, DH, 1.0f / nN);
    bnact_kernel<<<dim3(2048), blk, 0, stream>>>(A, scale, shift, nN * DH, DH, 0.0f);

    // ---- FF layer 2: B = A @ Wf2 ; BN + ReLU  (-> h) ----
    gemm_kernel<<<dim3(cdiv(nN, 64), DIN / 64), blk, 0, stream>>>(A, Wf2, B, nN, DIN, DH, 0);
    hipMemsetAsync(sums, 0, 2 * DH * sizeof(float), stream);
    colstats_kernel<<<dim3(1024), blk, 0, stream>>>(B, sums, sqs, nN * DIN, DIN);
    bnparam_kernel<<<dim3(1), blk, 0, stream>>>(sums, sqs, gf2, bef2, scale, shift, DIN, 1.0f / nN);
    bnact_kernel<<<dim3(2048), blk, 0, stream>>>(B, scale, shift, nN * DIN, DIN, 0.0f);

    // ---- SAGE layer 1: C = mean-gather(h) ; A = h@Ws1 + C@Wn1 ; BN + LeakyReLU -> h1 ----
    gather128_kernel<<<dim3(cdiv(nN * 64, 256)), blk, 0, stream>>>(B, rowstart, degi, csr, C, nN);
    gemm_kernel<<<dim3(cdiv(nN, 64), DH / 64), blk, 0, stream>>>(B, Ws1, A, nN, DH, DIN, 0);
    gemm_kernel<<<dim3(cdiv(nN, 64), DH / 64), blk, 0, stream>>>(C, Wn1, A, nN, DH, DIN, 1);
    hipMemsetAsync(sums, 0, 2 * DH * sizeof(float), stream);
    colstats_kernel<<<dim3(1024), blk, 0, stream>>>(A, sums, sqs, nN * DH, DH);
    bnparam_kernel<<<dim3(1), blk, 0, stream>>>(sums, sqs, gs1, bs1, scale, shift, DH, 1.0f / nN);
    bnact_kernel<<<dim3(2048), blk, 0, stream>>>(A, scale, shift, nN * DH, DH, 0.01f);

    // ---- SAGE layer 2 (transform-then-aggregate): y2 = h1@Wn2 ; out = gather(y2) ; out += h1@Ws2 ----
    gemm_kernel<<<dim3(cdiv(nN, 64), DOUT / 64), blk, 0, stream>>>(A, Wn2, B, nN, DOUT, DH, 0);
    gather128_kernel<<<dim3(cdiv(nN * 64, 256)), blk, 0, stream>>>(B, rowstart, degi, csr, out, nN);
    gemm_kernel<<<dim3(cdiv(nN, 64), DOUT / 64), blk, 0, stream>>>(A, Ws2, out, nN, DOUT, DH, 1);
    hipMemsetAsync(sums, 0, 2 * DH * sizeof(float), stream);
    colstats_kernel<<<dim3(1024), blk, 0, stream>>>(out, sums, sqs, nN * DOUT, DOUT);
    bnparam_kernel<<<dim3(1), blk, 0, stream>>>(sums, sqs, gs2, bs2, scale, shift, DOUT, 1.0f / nN);
    bnact_kernel<<<dim3(2048), blk, 0, stream>>>(out, scale, shift, nN * DOUT, DOUT, 0.01f);
}

// Round 3
// 815.272 us; speedup vs baseline: 2.0858x; 1.3211x over previous
//
#include <hip/hip_runtime.h>

#define DIN 128
#define DH  256
#define DOUT 128
#define BN_EPS 1e-5f

// ---------------- GEMM: C[M,N] = A[M,K] @ W[K,N]  (optional +=, optional fused col-stats) ----
__global__ __launch_bounds__(256) void gemm_kernel(
    const float* __restrict__ A, const float* __restrict__ W, float* __restrict__ C,
    int M, int N, int K, int accumulate,
    float* __restrict__ gsums, float* __restrict__ gsqs, int do_stats)
{
    const int BM = 64, BN = 64, BK = 16;
    __shared__ float As[BK][BM + 4];
    __shared__ float Bs[BK][BN + 4];
    __shared__ float s_sum[BN];
    __shared__ float s_sq[BN];

    int tid = threadIdx.x;
    int ty = tid >> 4;
    int tx = tid & 15;
    int rowBase = blockIdx.x * BM;
    int colBase = blockIdx.y * BN;

    int arow = tid >> 2;
    int acol = (tid & 3) * 4;
    int wrow = tid >> 4;
    int wcol = (tid & 15) * 4;

    float acc[4][4] = {};

    for (int k0 = 0; k0 < K; k0 += BK) {
        {
            int r = rowBase + arow;
            float4 v = make_float4(0.f, 0.f, 0.f, 0.f);
            if (r < M) v = *(const float4*)&A[(long)r * K + k0 + acol];
            As[acol + 0][arow] = v.x;
            As[acol + 1][arow] = v.y;
            As[acol + 2][arow] = v.z;
            As[acol + 3][arow] = v.w;
            float4 w = *(const float4*)&W[(long)(k0 + wrow) * N + colBase + wcol];
            *(float4*)&Bs[wrow][wcol] = w;
        }
        __syncthreads();
        #pragma unroll
        for (int kk = 0; kk < BK; kk++) {
            float4 a4 = *(const float4*)&As[kk][ty * 4];
            float4 b4 = *(const float4*)&Bs[kk][tx * 4];
            float av[4] = {a4.x, a4.y, a4.z, a4.w};
            float bv[4] = {b4.x, b4.y, b4.z, b4.w};
            #pragma unroll
            for (int i = 0; i < 4; i++)
                #pragma unroll
                for (int j = 0; j < 4; j++)
                    acc[i][j] += av[i] * bv[j];
        }
        __syncthreads();
    }

    // epilogue: finalize (+= old if accumulate), store, keep final values
    float fin[4][4];
    #pragma unroll
    for (int i = 0; i < 4; i++) {
        int r = rowBase + ty * 4 + i;
        if (r < M) {
            float* cp = &C[(long)r * N + colBase + tx * 4];
            float4 o;
            if (accumulate) {
                float4 old = *(const float4*)cp;
                o = make_float4(old.x + acc[i][0], old.y + acc[i][1],
                                old.z + acc[i][2], old.w + acc[i][3]);
            } else {
                o = make_float4(acc[i][0], acc[i][1], acc[i][2], acc[i][3]);
            }
            *(float4*)cp = o;
            fin[i][0] = o.x; fin[i][1] = o.y; fin[i][2] = o.z; fin[i][3] = o.w;
        } else {
            fin[i][0] = fin[i][1] = fin[i][2] = fin[i][3] = 0.f;
        }
    }

    // fused column stats: per-thread partials -> LDS reduce -> global atomic (1 per col per block)
    if (do_stats) {
        if (tid < BN) { s_sum[tid] = 0.f; s_sq[tid] = 0.f; }
        __syncthreads();
        #pragma unroll
        for (int j = 0; j < 4; j++) {
            float ps = 0.f, pq = 0.f;
            #pragma unroll
            for (int i = 0; i < 4; i++) {
                int r = rowBase + ty * 4 + i;
                if (r < M) { ps += fin[i][j]; pq += fin[i][j] * fin[i][j]; }
            }
            atomicAdd(&s_sum[tx * 4 + j], ps);
            atomicAdd(&s_sq[tx * 4 + j], pq);
        }
        __syncthreads();
        if (tid < BN) {
            atomicAdd(&gsums[colBase + tid], s_sum[tid]);
            atomicAdd(&gsqs[colBase + tid], s_sq[tid]);
        }
    }
}

__global__ void bnparam_kernel(const float* __restrict__ sums, const float* __restrict__ sqs,
                               const float* __restrict__ gamma, const float* __restrict__ beta,
                               float* __restrict__ scale, float* __restrict__ shift,
                               int N, float invM)
{
    int c = blockIdx.x * blockDim.x + threadIdx.x;
    if (c < N) {
        float mean = sums[c] * invM;
        float var = sqs[c] * invM - mean * mean;
        float sc = gamma[c] * rsqrtf(var + BN_EPS);
        scale[c] = sc;
        shift[c] = beta[c] - mean * sc;
    }
}

__global__ __launch_bounds__(256) void bnact_kernel(
    float* __restrict__ X, const float* __restrict__ scale, const float* __restrict__ shift,
    int total, int N, float negSlope)
{
    int stride = gridDim.x * blockDim.x;
    for (int i = blockIdx.x * blockDim.x + threadIdx.x; i < total; i += stride) {
        int c = i & (N - 1);
        float v = X[i] * scale[c] + shift[c];
        X[i] = (v > 0.f) ? v : v * negSlope;
    }
}

// ---------------- CSR build ----------------
__global__ void degcount_kernel(const int* __restrict__ dst, int* __restrict__ degi, int E)
{
    int i = blockIdx.x * blockDim.x + threadIdx.x;
    if (i < E) atomicAdd(&degi[dst[i]], 1);
}

__global__ __launch_bounds__(256) void scan_block_sums(const int* __restrict__ degi,
                                                       int* __restrict__ partial, int n)
{
    __shared__ int s[256];
    int i = blockIdx.x * 256 + threadIdx.x;
    s[threadIdx.x] = (i < n) ? degi[i] : 0;
    __syncthreads();
    for (int off = 128; off > 0; off >>= 1) {
        if (threadIdx.x < off) s[threadIdx.x] += s[threadIdx.x + off];
        __syncthreads();
    }
    if (threadIdx.x == 0) partial[blockIdx.x] = s[0];
}

__global__ __launch_bounds__(256) void scan_partials(int* __restrict__ partial, int nb)
{
    __shared__ int s[256];
    int v = (threadIdx.x < nb) ? partial[threadIdx.x] : 0;
    s[threadIdx.x] = v;
    __syncthreads();
    for (int off = 1; off < 256; off <<= 1) {
        int t = (threadIdx.x >= off) ? s[threadIdx.x - off] : 0;
        __syncthreads();
        s[threadIdx.x] += t;
        __syncthreads();
    }
    if (threadIdx.x < nb) partial[threadIdx.x] = s[threadIdx.x] - v;  // exclusive
}

__global__ __launch_bounds__(256) void scan_final(const int* __restrict__ degi,
                                                  const int* __restrict__ partial,
                                                  int* __restrict__ rowstart, int n)
{
    __shared__ int s[256];
    int i = blockIdx.x * 256 + threadIdx.x;
    int v = (i < n) ? degi[i] : 0;
    s[threadIdx.x] = v;
    __syncthreads();
    for (int off = 1; off < 256; off <<= 1) {
        int t = (threadIdx.x >= off) ? s[threadIdx.x - off] : 0;
        __syncthreads();
        s[threadIdx.x] += t;
        __syncthreads();
    }
    if (i < n) rowstart[i] = partial[blockIdx.x] + s[threadIdx.x] - v;  // exclusive
}

__global__ void fillcsr_kernel(const int* __restrict__ src, const int* __restrict__ dst,
                               const int* __restrict__ rowstart, int* __restrict__ cursor,
                               int* __restrict__ csr, int E)
{
    int i = blockIdx.x * blockDim.x + threadIdx.x;
    if (i < E) {
        int d = dst[i];
        int p = atomicAdd(&cursor[d], 1);
        csr[rowstart[d] + p] = src[i];
    }
}

// ---------------- gather mean-aggregation: one wave per dst node, D=128 ----------------
__global__ __launch_bounds__(256) void gather128_kernel(
    const float* __restrict__ X, const int* __restrict__ rowstart,
    const int* __restrict__ degi, const int* __restrict__ csr,
    float* __restrict__ O, int nN)
{
    int wave = (blockIdx.x * blockDim.x + threadIdx.x) >> 6;
    int lane = threadIdx.x & 63;
    if (wave >= nN) return;
    int start = rowstart[wave];
    int d = degi[wave];
    float2 acc = make_float2(0.f, 0.f);
    const int col = lane * 2;
    for (int j = 0; j < d; j++) {
        int s = csr[start + j];
        float2 v = *(const float2*)&X[(long)s * 128 + col];
        acc.x += v.x;
        acc.y += v.y;
    }
    float inv = 1.0f / fmaxf((float)d, 1.0f);
    *(float2*)&O[(long)wave * 128 + col] = make_float2(acc.x * inv, acc.y * inv);
}

extern "C" void kernel_launch(void* const* d_in, const int* in_sizes, int n_in,
                              void* d_out, int out_size, void* d_ws, size_t ws_size,
                              hipStream_t stream)
{
    const float* nodes = (const float*)d_in[0];
    const int*   src   = (const int*)d_in[1];
    const int*   dst   = (const int*)d_in[2];
    const float* Wf1   = (const float*)d_in[3];
    const float* gf1   = (const float*)d_in[5];
    const float* bef1  = (const float*)d_in[6];
    const float* Wf2   = (const float*)d_in[7];
    const float* gf2   = (const float*)d_in[9];
    const float* bef2  = (const float*)d_in[10];
    const float* Ws1   = (const float*)d_in[11];
    const float* Wn1   = (const float*)d_in[12];
    const float* gs1   = (const float*)d_in[14];
    const float* bs1   = (const float*)d_in[15];
    const float* Ws2   = (const float*)d_in[16];
    const float* Wn2   = (const float*)d_in[17];
    const float* gs2   = (const float*)d_in[19];
    const float* bs2   = (const float*)d_in[20];
    // pre-BN biases (bf1,bf2,b1,b2) cancel under BatchNorm -> skipped

    int nN = in_sizes[0] / DIN;   // 50000
    int nE = in_sizes[1];         // 600000
    float* out = (float*)d_out;

    float* A    = (float*)d_ws;                    // nN*DH
    float* B    = A + (size_t)nN * DH;             // nN*DIN
    float* C    = B + (size_t)nN * DIN;            // nN*DIN
    float* sums = C + (size_t)nN * DIN;            // DH
    float* sqs  = sums + DH;
    float* scale= sqs + DH;
    float* shift= scale + DH;
    int* degi     = (int*)(shift + DH);            // nN
    int* rowstart = degi + nN;                     // nN
    int* cursor   = rowstart + nN;                 // nN
    int* partial  = cursor + nN;                   // 256
    int* csr      = partial + 256;                 // nE

    dim3 blk(256);
    auto cdiv = [](int a, int b) { return (a + b - 1) / b; };
    int nScanBlocks = cdiv(nN, 256);

    // ---- CSR build (once, reused by both layers) ----
    hipMemsetAsync(degi, 0, (size_t)nN * sizeof(int), stream);
    hipMemsetAsync(cursor, 0, (size_t)nN * sizeof(int), stream);
    degcount_kernel<<<dim3(cdiv(nE, 256)), blk, 0, stream>>>(dst, degi, nE);
    scan_block_sums<<<dim3(nScanBlocks), blk, 0, stream>>>(degi, partial, nN);
    scan_partials<<<dim3(1), blk, 0, stream>>>(partial, nScanBlocks);
    scan_final<<<dim3(nScanBlocks), blk, 0, stream>>>(degi, partial, rowstart, nN);
    fillcsr_kernel<<<dim3(cdiv(nE, 256)), blk, 0, stream>>>(src, dst, rowstart, cursor, csr, nE);

    // ---- FF layer 1: A = nodes @ Wf1 (stats fused) ; BN + ReLU ----
    hipMemsetAsync(sums, 0, 2 * DH * sizeof(float), stream);
    gemm_kernel<<<dim3(cdiv(nN, 64), DH / 64), blk, 0, stream>>>(nodes, Wf1, A, nN, DH, DIN, 0, sums, sqs, 1);
    bnparam_kernel<<<dim3(1), blk, 0, stream>>>(sums, sqs, gf1, bef1, scale, shift, DH, 1.0f / nN);
    bnact_kernel<<<dim3(2048), blk, 0, stream>>>(A, scale, shift, nN * DH, DH, 0.0f);

    // ---- FF layer 2: B = A @ Wf2 (stats fused) ; BN + ReLU -> h ----
    hipMemsetAsync(sums, 0, 2 * DH * sizeof(float), stream);
    gemm_kernel<<<dim3(cdiv(nN, 64), DIN / 64), blk, 0, stream>>>(A, Wf2, B, nN, DIN, DH, 0, sums, sqs, 1);
    bnparam_kernel<<<dim3(1), blk, 0, stream>>>(sums, sqs, gf2, bef2, scale, shift, DIN, 1.0f / nN);
    bnact_kernel<<<dim3(2048), blk, 0, stream>>>(B, scale, shift, nN * DIN, DIN, 0.0f);

    // ---- SAGE layer 1: C = mean-gather(h) ; A = h@Ws1 + C@Wn1 (stats on accum) ; BN+LReLU -> h1 ----
    gather128_kernel<<<dim3(cdiv(nN * 64, 256)), blk, 0, stream>>>(B, rowstart, degi, csr, C, nN);
    hipMemsetAsync(sums, 0, 2 * DH * sizeof(float), stream);
    gemm_kernel<<<dim3(cdiv(nN, 64), DH / 64), blk, 0, stream>>>(B, Ws1, A, nN, DH, DIN, 0, sums, sqs, 0);
    gemm_kernel<<<dim3(cdiv(nN, 64), DH / 64), blk, 0, stream>>>(C, Wn1, A, nN, DH, DIN, 1, sums, sqs, 1);
    bnparam_kernel<<<dim3(1), blk, 0, stream>>>(sums, sqs, gs1, bs1, scale, shift, DH, 1.0f / nN);
    bnact_kernel<<<dim3(2048), blk, 0, stream>>>(A, scale, shift, nN * DH, DH, 0.01f);

    // ---- SAGE layer 2 (transform-then-aggregate): y2 = h1@Wn2 ; out = gather(y2) ; out += h1@Ws2 (stats) ----
    gemm_kernel<<<dim3(cdiv(nN, 64), DOUT / 64), blk, 0, stream>>>(A, Wn2, B, nN, DOUT, DH, 0, sums, sqs, 0);
    gather128_kernel<<<dim3(cdiv(nN * 64, 256)), blk, 0, stream>>>(B, rowstart, degi, csr, out, nN);
    hipMemsetAsync(sums, 0, 2 * DH * sizeof(float), stream);
    gemm_kernel<<<dim3(cdiv(nN, 64), DOUT / 64), blk, 0, stream>>>(A, Ws2, out, nN, DOUT, DH, 1, sums, sqs, 1);
    bnparam_kernel<<<dim3(1), blk, 0, stream>>>(sums, sqs, gs2, bs2, scale, shift, DOUT, 1.0f / nN);
    bnact_kernel<<<dim3(2048), blk, 0, stream>>>(out, scale, shift, nN * DOUT, DOUT, 0.01f);
}

// Round 4
// 573.301 us; speedup vs baseline: 2.9661x; 1.4221x over previous
//
#include <hip/hip_runtime.h>

#define DIN 128
#define DH  256
#define BN_EPS 1e-5f

typedef __attribute__((ext_vector_type(8))) short bf16x8;
typedef __attribute__((ext_vector_type(4))) float f32x4;

__device__ __forceinline__ ushort f2bf(float f) {
    unsigned u = __float_as_uint(f);
    u += 0x7fffu + ((u >> 16) & 1u);
    return (ushort)(u >> 16);
}
__device__ __forceinline__ float bf2f(ushort h) {
    return __uint_as_float(((unsigned)h) << 16);
}

// ======== MFMA GEMM: C[M,N] = A[M,K](bf16) @ BT[N,K](bf16)^T ========
// 128x128 tile, BK=64, 256 threads = 4 waves (2x2), 16x16x32 MFMA.
// Optional fused column stats (global atomics) and bf16 output.
__global__ __launch_bounds__(256) void mfma_gemm(
    const ushort* __restrict__ A, const ushort* __restrict__ BT,
    float* __restrict__ C32, ushort* __restrict__ Cb16,
    int M, int N, int K, int outBF, int do_stats,
    float* __restrict__ gsums, float* __restrict__ gsqs)
{
    __shared__ ushort As[8192];   // [ksub(2)][mtile(8)][lane(64)][8]
    __shared__ ushort Bs[8192];
    __shared__ float s_sum[128], s_sq[128];

    int tid = threadIdx.x;
    int rowBase = blockIdx.x * 128;
    int colBase = blockIdx.y * 128;
    int wave = tid >> 6, lane = tid & 63;
    int wr = wave >> 1, wc = wave & 1;

    f32x4 acc[4][4] = {};

    for (int k0 = 0; k0 < K; k0 += 64) {
        #pragma unroll
        for (int p = 0; p < 4; p++) {
            int c = tid + p * 256;
            int row = (c & 15) | ((c >> 7) << 4);   // 0..127
            int q = (c >> 4) & 7;                    // 0..7 (16B chunk along k)
            int ksub = q >> 2, quad = q & 3;
            int li = ((ksub * 8 + (row >> 4)) * 64 + (quad * 16 + (row & 15))) * 8;
            int rg = rowBase + row; if (rg > M - 1) rg = M - 1;
            *(bf16x8*)(As + li) = *(const bf16x8*)(A + (long)rg * K + k0 + q * 8);
            *(bf16x8*)(Bs + li) = *(const bf16x8*)(BT + (long)(colBase + row) * K + k0 + q * 8);
        }
        __syncthreads();
        #pragma unroll
        for (int ks = 0; ks < 2; ks++) {
            bf16x8 af[4], bfr[4];
            #pragma unroll
            for (int i = 0; i < 4; i++)
                af[i] = *(const bf16x8*)(As + ((ks * 8 + wr * 4 + i) * 64 + lane) * 8);
            #pragma unroll
            for (int j = 0; j < 4; j++)
                bfr[j] = *(const bf16x8*)(Bs + ((ks * 8 + wc * 4 + j) * 64 + lane) * 8);
            #pragma unroll
            for (int i = 0; i < 4; i++)
                #pragma unroll
                for (int j = 0; j < 4; j++)
                    acc[i][j] = __builtin_amdgcn_mfma_f32_16x16x32_bf16(af[i], bfr[j], acc[i][j], 0, 0, 0);
        }
        __syncthreads();
    }

    // epilogue: C/D layout col=lane&15, row=(lane>>4)*4+reg
    if (do_stats) {
        if (tid < 128) { s_sum[tid] = 0.f; s_sq[tid] = 0.f; }
        __syncthreads();
    }
    int q4 = lane >> 4, cl = lane & 15;
    #pragma unroll
    for (int i = 0; i < 4; i++) {
        #pragma unroll
        for (int j = 0; j < 4; j++) {
            int colL = wc * 64 + j * 16 + cl;
            long col = colBase + colL;
            float ps = 0.f, pq = 0.f;
            #pragma unroll
            for (int r = 0; r < 4; r++) {
                long row = rowBase + wr * 64 + i * 16 + q4 * 4 + r;
                float v = acc[i][j][r];
                if (row < M) {
                    if (outBF) Cb16[row * N + col] = f2bf(v);
                    else       C32[row * N + col] = v;
                    ps += v; pq += v * v;
                }
            }
            if (do_stats) {
                atomicAdd(&s_sum[colL], ps);
                atomicAdd(&s_sq[colL], pq);
            }
        }
    }
    if (do_stats) {
        __syncthreads();
        if (tid < 128) {
            atomicAdd(&gsums[colBase + tid], s_sum[tid]);
            atomicAdd(&gsqs[colBase + tid], s_sq[tid]);
        }
    }
}

// ======== BN params ========
__global__ void bnparam_kernel(const float* __restrict__ sums, const float* __restrict__ sqs,
                               const float* __restrict__ gamma, const float* __restrict__ beta,
                               float* __restrict__ scale, float* __restrict__ shift,
                               int N, float invM)
{
    int c = blockIdx.x * blockDim.x + threadIdx.x;
    if (c < N) {
        float mean = sums[c] * invM;
        float var = sqs[c] * invM - mean * mean;
        float sc = gamma[c] * rsqrtf(var + BN_EPS);
        scale[c] = sc;
        shift[c] = beta[c] - mean * sc;
    }
}

// ======== BN + act, fp32 -> bf16 (vectorized x4), strided output ========
__global__ __launch_bounds__(256) void bnact_bf(
    const float* __restrict__ X, const float* __restrict__ scale, const float* __restrict__ shift,
    ushort* __restrict__ O, int total4, int logN, int outStride, float negSlope)
{
    int stride = gridDim.x * blockDim.x;
    int Nm1 = (1 << logN) - 1;
    for (int t = blockIdx.x * blockDim.x + threadIdx.x; t < total4; t += stride) {
        int idx = t * 4;
        int row = idx >> logN;
        int c = idx & Nm1;
        float4 v = *(const float4*)&X[idx];
        float4 sc = *(const float4*)&scale[c];
        float4 sh = *(const float4*)&shift[c];
        float a = v.x * sc.x + sh.x; a = (a > 0.f) ? a : a * negSlope;
        float b = v.y * sc.y + sh.y; b = (b > 0.f) ? b : b * negSlope;
        float d = v.z * sc.z + sh.z; d = (d > 0.f) ? d : d * negSlope;
        float e = v.w * sc.w + sh.w; e = (e > 0.f) ? e : e * negSlope;
        ushort4 o; o.x = f2bf(a); o.y = f2bf(b); o.z = f2bf(d); o.w = f2bf(e);
        *(ushort4*)&O[(long)row * outStride + c] = o;
    }
}

// ======== BN + act, fp32 in-place (final output) ========
__global__ __launch_bounds__(256) void bnact_f32(
    float* __restrict__ X, const float* __restrict__ scale, const float* __restrict__ shift,
    int total4, int logN, float negSlope)
{
    int stride = gridDim.x * blockDim.x;
    int Nm1 = (1 << logN) - 1;
    for (int t = blockIdx.x * blockDim.x + threadIdx.x; t < total4; t += stride) {
        int idx = t * 4;
        int c = idx & Nm1;
        float4 v = *(const float4*)&X[idx];
        float4 sc = *(const float4*)&scale[c];
        float4 sh = *(const float4*)&shift[c];
        float a = v.x * sc.x + sh.x; a = (a > 0.f) ? a : a * negSlope;
        float b = v.y * sc.y + sh.y; b = (b > 0.f) ? b : b * negSlope;
        float d = v.z * sc.z + sh.z; d = (d > 0.f) ? d : d * negSlope;
        float e = v.w * sc.w + sh.w; e = (e > 0.f) ? e : e * negSlope;
        *(float4*)&X[idx] = make_float4(a, b, d, e);
    }
}

// ======== column stats for final output (128 cols, register accum) ========
__global__ __launch_bounds__(256) void colstats128(
    const float* __restrict__ X, float* __restrict__ sums, float* __restrict__ sqs, int M)
{
    __shared__ float ss[128], sq[128];
    int tid = threadIdx.x;
    if (tid < 128) { ss[tid] = 0.f; sq[tid] = 0.f; }
    __syncthreads();
    int cg = tid & 31;                       // 4-col group
    int worker = (blockIdx.x << 3) | (tid >> 5);
    int totalW = gridDim.x << 3;
    float4 s4 = make_float4(0, 0, 0, 0), q4 = make_float4(0, 0, 0, 0);
    for (int r = worker; r < M; r += totalW) {
        float4 v = *(const float4*)&X[(long)r * 128 + cg * 4];
        s4.x += v.x; s4.y += v.y; s4.z += v.z; s4.w += v.w;
        q4.x += v.x * v.x; q4.y += v.y * v.y; q4.z += v.z * v.z; q4.w += v.w * v.w;
    }
    atomicAdd(&ss[cg * 4 + 0], s4.x); atomicAdd(&sq[cg * 4 + 0], q4.x);
    atomicAdd(&ss[cg * 4 + 1], s4.y); atomicAdd(&sq[cg * 4 + 1], q4.y);
    atomicAdd(&ss[cg * 4 + 2], s4.z); atomicAdd(&sq[cg * 4 + 2], q4.z);
    atomicAdd(&ss[cg * 4 + 3], s4.w); atomicAdd(&sq[cg * 4 + 3], q4.w);
    __syncthreads();
    if (tid < 128) { atomicAdd(&sums[tid], ss[tid]); atomicAdd(&sqs[tid], sq[tid]); }
}

// ======== converts ========
__global__ void convert_nodes(const float* __restrict__ X, ushort* __restrict__ O, int total4)
{
    int t = blockIdx.x * blockDim.x + threadIdx.x;
    if (t < total4) {
        float4 v = *(const float4*)&X[t * 4];
        ushort4 o; o.x = f2bf(v.x); o.y = f2bf(v.y); o.z = f2bf(v.z); o.w = f2bf(v.w);
        *(ushort4*)&O[t * 4] = o;
    }
}

// WT[n*dstStride + dstOff + k] = bf16(W[k*N + n]),  k<K, n<N
__global__ void wt_part(const float* __restrict__ W, ushort* __restrict__ WT,
                        int logK, int N, int dstStride, int dstOff, int total)
{
    int t = blockIdx.x * blockDim.x + threadIdx.x;
    if (t < total) {
        int k = t & ((1 << logK) - 1);
        int n = t >> logK;
        WT[(long)n * dstStride + dstOff + k] = f2bf(W[(long)k * N + n]);
    }
}

// ======== CSR build ========
__global__ void degcount_kernel(const int* __restrict__ dst, int* __restrict__ degi, int E)
{
    int i = blockIdx.x * blockDim.x + threadIdx.x;
    if (i < E) atomicAdd(&degi[dst[i]], 1);
}

__global__ __launch_bounds__(256) void scan_block_sums(const int* __restrict__ degi,
                                                       int* __restrict__ partial, int n)
{
    __shared__ int s[256];
    int i = blockIdx.x * 256 + threadIdx.x;
    s[threadIdx.x] = (i < n) ? degi[i] : 0;
    __syncthreads();
    for (int off = 128; off > 0; off >>= 1) {
        if (threadIdx.x < off) s[threadIdx.x] += s[threadIdx.x + off];
        __syncthreads();
    }
    if (threadIdx.x == 0) partial[blockIdx.x] = s[0];
}

__global__ __launch_bounds__(256) void scan_partials(int* __restrict__ partial, int nb)
{
    __shared__ int s[256];
    int v = (threadIdx.x < nb) ? partial[threadIdx.x] : 0;
    s[threadIdx.x] = v;
    __syncthreads();
    for (int off = 1; off < 256; off <<= 1) {
        int t = (threadIdx.x >= off) ? s[threadIdx.x - off] : 0;
        __syncthreads();
        s[threadIdx.x] += t;
        __syncthreads();
    }
    if (threadIdx.x < nb) partial[threadIdx.x] = s[threadIdx.x] - v;
}

__global__ __launch_bounds__(256) void scan_final(const int* __restrict__ degi,
                                                  const int* __restrict__ partial,
                                                  int* __restrict__ rowstart, int n)
{
    __shared__ int s[256];
    int i = blockIdx.x * 256 + threadIdx.x;
    int v = (i < n) ? degi[i] : 0;
    s[threadIdx.x] = v;
    __syncthreads();
    for (int off = 1; off < 256; off <<= 1) {
        int t = (threadIdx.x >= off) ? s[threadIdx.x - off] : 0;
        __syncthreads();
        s[threadIdx.x] += t;
        __syncthreads();
    }
    if (i < n) rowstart[i] = partial[blockIdx.x] + s[threadIdx.x] - v;
}

__global__ void fillcsr_kernel(const int* __restrict__ src, const int* __restrict__ dst,
                               const int* __restrict__ rowstart, int* __restrict__ cursor,
                               int* __restrict__ csr, int E)
{
    int i = blockIdx.x * blockDim.x + threadIdx.x;
    if (i < E) {
        int d = dst[i];
        int p = atomicAdd(&cursor[d], 1);
        csr[rowstart[d] + p] = src[i];
    }
}

// ======== gather mean (bf16 in, bf16 out), one wave per node, D=128 ========
__global__ __launch_bounds__(256) void gather_bf(
    const ushort* __restrict__ X, const int* __restrict__ rowstart,
    const int* __restrict__ degi, const int* __restrict__ csr,
    ushort* __restrict__ O, int nN)
{
    int wv = (blockIdx.x * blockDim.x + threadIdx.x) >> 6;
    int lane = threadIdx.x & 63;
    if (wv >= nN) return;
    int start = rowstart[wv], d = degi[wv];
    float a0 = 0.f, a1 = 0.f;
    int col = lane * 2;
    for (int j = 0; j < d; j++) {
        int s = csr[start + j];
        unsigned pv = *(const unsigned*)(X + (long)s * 256 + col);
        a0 += bf2f((ushort)(pv & 0xffff));
        a1 += bf2f((ushort)(pv >> 16));
    }
    float inv = 1.f / fmaxf((float)d, 1.f);
    unsigned o = (unsigned)f2bf(a0 * inv) | ((unsigned)f2bf(a1 * inv) << 16);
    *(unsigned*)(O + (long)wv * 256 + col) = o;
}

// ======== fused gather2: out = mean(Z[src, 0:128]) + Z[dst, 128:256]  (fp32 out) ========
__global__ __launch_bounds__(256) void gather_fuse(
    const ushort* __restrict__ Z, const int* __restrict__ rowstart,
    const int* __restrict__ degi, const int* __restrict__ csr,
    float* __restrict__ O, int nN)
{
    int wv = (blockIdx.x * blockDim.x + threadIdx.x) >> 6;
    int lane = threadIdx.x & 63;
    if (wv >= nN) return;
    int start = rowstart[wv], d = degi[wv];
    float a0 = 0.f, a1 = 0.f;
    int col = lane * 2;
    for (int j = 0; j < d; j++) {
        int s = csr[start + j];
        unsigned pv = *(const unsigned*)(Z + (long)s * 256 + col);
        a0 += bf2f((ushort)(pv & 0xffff));
        a1 += bf2f((ushort)(pv >> 16));
    }
    float inv = 1.f / fmaxf((float)d, 1.f);
    unsigned sv = *(const unsigned*)(Z + (long)wv * 256 + 128 + col);
    float s0 = bf2f((ushort)(sv & 0xffff));
    float s1 = bf2f((ushort)(sv >> 16));
    *(float2*)(O + (long)wv * 128 + col) = make_float2(a0 * inv + s0, a1 * inv + s1);
}

extern "C" void kernel_launch(void* const* d_in, const int* in_sizes, int n_in,
                              void* d_out, int out_size, void* d_ws, size_t ws_size,
                              hipStream_t stream)
{
    const float* nodes = (const float*)d_in[0];
    const int*   src   = (const int*)d_in[1];
    const int*   dst   = (const int*)d_in[2];
    const float* Wf1   = (const float*)d_in[3];
    const float* gf1   = (const float*)d_in[5];
    const float* bef1  = (const float*)d_in[6];
    const float* Wf2   = (const float*)d_in[7];
    const float* gf2   = (const float*)d_in[9];
    const float* bef2  = (const float*)d_in[10];
    const float* Ws1   = (const float*)d_in[11];
    const float* Wn1   = (const float*)d_in[12];
    const float* gs1   = (const float*)d_in[14];
    const float* bs1   = (const float*)d_in[15];
    const float* Ws2   = (const float*)d_in[16];
    const float* Wn2   = (const float*)d_in[17];
    const float* gs2   = (const float*)d_in[19];
    const float* bs2   = (const float*)d_in[20];
    // pre-BN biases (bf1,bf2,b1,b2) cancel under BatchNorm -> skipped

    int nN = in_sizes[0] / DIN;   // 50000
    int nE = in_sizes[1];         // 600000
    float* out = (float*)d_out;

    // ---- workspace layout ----
    float* T32  = (float*)d_ws;                      // M*256 fp32
    ushort* BF1 = (ushort*)(T32 + (size_t)nN * 256); // M*256 bf16 (Xn / Abf / h1)
    ushort* BF2 = BF1 + (size_t)nN * 256;            // M*256 bf16 ([h|agg] / Z)
    float* sums = (float*)(BF2 + (size_t)nN * 256);  // 256
    float* sqs  = sums + 256;
    float* scale= sqs + 256;
    float* shift= scale + 256;
    ushort* Wf1T = (ushort*)(shift + 256);           // 256*128
    ushort* Wf2T = Wf1T + 256 * 128;                 // 128*256
    ushort* Wc1T = Wf2T + 128 * 256;                 // 256*256 [Ws1;Wn1]
    ushort* Wc2T = Wc1T + 256 * 256;                 // 256*256 [Wn2|Ws2]
    int* degi     = (int*)(Wc2T + 256 * 256);        // nN
    int* rowstart = degi + nN;
    int* cursor   = rowstart + nN;
    int* partial  = cursor + nN;                     // 256
    int* csr      = partial + 256;                   // nE

    dim3 blk(256);
    auto cdiv = [](int a, int b) { return (a + b - 1) / b; };
    int gM = cdiv(nN, 128);           // 391
    int nScanBlocks = cdiv(nN, 256);

    // ---- converts ----
    convert_nodes<<<dim3(cdiv(nN * DIN / 4, 256)), blk, 0, stream>>>(nodes, BF1, nN * DIN / 4);
    wt_part<<<dim3(128), blk, 0, stream>>>(Wf1, Wf1T, 7, 256, 128, 0, 32768);
    wt_part<<<dim3(128), blk, 0, stream>>>(Wf2, Wf2T, 8, 128, 256, 0, 32768);
    wt_part<<<dim3(128), blk, 0, stream>>>(Ws1, Wc1T, 7, 256, 256, 0, 32768);
    wt_part<<<dim3(128), blk, 0, stream>>>(Wn1, Wc1T, 7, 256, 256, 128, 32768);
    wt_part<<<dim3(128), blk, 0, stream>>>(Wn2, Wc2T, 8, 128, 256, 0, 32768);
    wt_part<<<dim3(128), blk, 0, stream>>>(Ws2, Wc2T + 128 * 256, 8, 128, 256, 0, 32768);

    // ---- CSR build ----
    hipMemsetAsync(degi, 0, (size_t)nN * sizeof(int), stream);
    hipMemsetAsync(cursor, 0, (size_t)nN * sizeof(int), stream);
    degcount_kernel<<<dim3(cdiv(nE, 256)), blk, 0, stream>>>(dst, degi, nE);
    scan_block_sums<<<dim3(nScanBlocks), blk, 0, stream>>>(degi, partial, nN);
    scan_partials<<<dim3(1), blk, 0, stream>>>(partial, nScanBlocks);
    scan_final<<<dim3(nScanBlocks), blk, 0, stream>>>(degi, partial, rowstart, nN);
    fillcsr_kernel<<<dim3(cdiv(nE, 256)), blk, 0, stream>>>(src, dst, rowstart, cursor, csr, nE);

    // ---- FF1: T32 = Xn @ Wf1T (stats) ; BN+ReLU -> BF1 (M x 256 bf16) ----
    hipMemsetAsync(sums, 0, 2 * 256 * sizeof(float), stream);
    mfma_gemm<<<dim3(gM, 2), blk, 0, stream>>>(BF1, Wf1T, T32, nullptr, nN, 256, 128, 0, 1, sums, sqs);
    bnparam_kernel<<<dim3(1), blk, 0, stream>>>(sums, sqs, gf1, bef1, scale, shift, 256, 1.0f / nN);
    bnact_bf<<<dim3(2048), blk, 0, stream>>>(T32, scale, shift, BF1, nN * 256 / 4, 8, 256, 0.0f);

    // ---- FF2: T32 = BF1 @ Wf2T (stats) ; BN+ReLU -> BF2[:,0:128] (h) ----
    hipMemsetAsync(sums, 0, 2 * 256 * sizeof(float), stream);
    mfma_gemm<<<dim3(gM, 1), blk, 0, stream>>>(BF1, Wf2T, T32, nullptr, nN, 128, 256, 0, 1, sums, sqs);
    bnparam_kernel<<<dim3(1), blk, 0, stream>>>(sums, sqs, gf2, bef2, scale, shift, 128, 1.0f / nN);
    bnact_bf<<<dim3(2048), blk, 0, stream>>>(T32, scale, shift, BF2, nN * 128 / 4, 7, 256, 0.0f);

    // ---- gather1: BF2[:,128:256] = mean-gather(BF2[:,0:128]) ----
    gather_bf<<<dim3(cdiv(nN * 64, 256)), blk, 0, stream>>>(BF2, rowstart, degi, csr, BF2 + 128, nN);

    // ---- SAGE1: T32 = [h|agg] @ [Ws1;Wn1] (K=256, stats) ; BN+LReLU -> BF1 (h1) ----
    hipMemsetAsync(sums, 0, 2 * 256 * sizeof(float), stream);
    mfma_gemm<<<dim3(gM, 2), blk, 0, stream>>>(BF2, Wc1T, T32, nullptr, nN, 256, 256, 0, 1, sums, sqs);
    bnparam_kernel<<<dim3(1), blk, 0, stream>>>(sums, sqs, gs1, bs1, scale, shift, 256, 1.0f / nN);
    bnact_bf<<<dim3(2048), blk, 0, stream>>>(T32, scale, shift, BF1, nN * 256 / 4, 8, 256, 0.01f);

    // ---- SAGE2: BF2 = h1 @ [Wn2|Ws2] (bf16 out) ; gather_fuse -> out ----
    mfma_gemm<<<dim3(gM, 2), blk, 0, stream>>>(BF1, Wc2T, nullptr, BF2, nN, 256, 256, 1, 0, sums, sqs);
    gather_fuse<<<dim3(cdiv(nN * 64, 256)), blk, 0, stream>>>(BF2, rowstart, degi, csr, out, nN);

    // ---- final BN+LReLU on out ----
    hipMemsetAsync(sums, 0, 2 * 256 * sizeof(float), stream);
    colstats128<<<dim3(120), blk, 0, stream>>>(out, sums, sqs, nN);
    bnparam_kernel<<<dim3(1), blk, 0, stream>>>(sums, sqs, gs2, bs2, scale, shift, 128, 1.0f / nN);
    bnact_f32<<<dim3(2048), blk, 0, stream>>>(out, scale, shift, nN * 128 / 4, 7, 0.01f);
}

// Round 5
// 555.145 us; speedup vs baseline: 3.0631x; 1.0327x over previous
//
#include <hip/hip_runtime.h>

#define DIN 128
#define BN_EPS 1e-5f

typedef __attribute__((ext_vector_type(8))) short bf16x8;
typedef __attribute__((ext_vector_type(4))) float f32x4;
typedef unsigned int u32;

__device__ __forceinline__ ushort f2bf(float f) {
    unsigned u = __float_as_uint(f);
    u += 0x7fffu + ((u >> 16) & 1u);
    return (ushort)(u >> 16);
}
__device__ __forceinline__ float bf2f(ushort h) {
    return __uint_as_float(((unsigned)h) << 16);
}

// ======== MFMA GEMM: C[M,N](bf16) = A[M,K](bf16) @ BT[N,K](bf16)^T ========
// 128x128 tile, BK=64, 256 threads = 4 waves (2x2), 16x16x32 MFMA.
// Staging via global_load_lds (async DMA, 16B/lane). Stats from fp32 pre-round.
__global__ __launch_bounds__(256) void mfma_gemm(
    const ushort* __restrict__ A, const ushort* __restrict__ BT,
    ushort* __restrict__ C, int M, int N, int K, int do_stats,
    float* __restrict__ gsums, float* __restrict__ gsqs)
{
    // chunk c = ks*8+mt (1KB each): holds rows mt*16+(lane&15), k = ks*32+(lane>>4)*8..+8
    __shared__ ushort As[8192];
    __shared__ ushort Bs[8192];

    int tid = threadIdx.x;
    int rowBase = blockIdx.x * 128;
    int colBase = blockIdx.y * 128;
    int wave = tid >> 6, lane = tid & 63;
    int wr = wave >> 1, wc = wave & 1;
    int r15 = lane & 15, q = lane >> 4;

    // per-wave: 4 A-chunks + 4 B-chunks; precompute per-lane global bases
    const ushort* gA[4];
    const ushort* gB[4];
    int cbase = wave * 4;
    #pragma unroll
    for (int cc = 0; cc < 4; cc++) {
        int c = cbase + cc;
        int mt = c & 7, ks = c >> 3;
        int ar = rowBase + mt * 16 + r15; if (ar >= M) ar = M - 1;
        int kc = ks * 32 + q * 8;
        gA[cc] = A + (long)ar * K + kc;
        gB[cc] = BT + (long)(colBase + mt * 16 + r15) * K + kc;
    }

    f32x4 acc[4][4] = {};

    for (int k0 = 0; k0 < K; k0 += 64) {
        #pragma unroll
        for (int cc = 0; cc < 4; cc++) {
            int c = cbase + cc;
            __builtin_amdgcn_global_load_lds(
                (const __attribute__((address_space(1))) u32*)gA[cc],
                (__attribute__((address_space(3))) u32*)(As + c * 512), 16, 0, 0);
            __builtin_amdgcn_global_load_lds(
                (const __attribute__((address_space(1))) u32*)gB[cc],
                (__attribute__((address_space(3))) u32*)(Bs + c * 512), 16, 0, 0);
            gA[cc] += 64; gB[cc] += 64;
        }
        __syncthreads();
        #pragma unroll
        for (int ks = 0; ks < 2; ks++) {
            bf16x8 af[4], bfr[4];
            #pragma unroll
            for (int i = 0; i < 4; i++)
                af[i] = *(const bf16x8*)(As + ((ks * 8 + wr * 4 + i) * 64 + lane) * 8);
            #pragma unroll
            for (int j = 0; j < 4; j++)
                bfr[j] = *(const bf16x8*)(Bs + ((ks * 8 + wc * 4 + j) * 64 + lane) * 8);
            #pragma unroll
            for (int i = 0; i < 4; i++)
                #pragma unroll
                for (int j = 0; j < 4; j++)
                    acc[i][j] = __builtin_amdgcn_mfma_f32_16x16x32_bf16(af[i], bfr[j], acc[i][j], 0, 0, 0);
        }
        __syncthreads();
    }

    // epilogue: C/D layout col=lane&15, row=(lane>>4)*4+reg ; stats LDS aliased into As
    float* s_sum = (float*)As;            // 128 floats
    float* s_sq  = (float*)As + 128;      // 128 floats
    if (do_stats) {
        if (tid < 128) { s_sum[tid] = 0.f; s_sq[tid] = 0.f; }
        __syncthreads();
    }
    #pragma unroll
    for (int i = 0; i < 4; i++) {
        #pragma unroll
        for (int j = 0; j < 4; j++) {
            int colL = wc * 64 + j * 16 + r15;
            long col = colBase + colL;
            float ps = 0.f, pq = 0.f;
            #pragma unroll
            for (int r = 0; r < 4; r++) {
                long row = rowBase + wr * 64 + i * 16 + q * 4 + r;
                float v = acc[i][j][r];
                if (row < M) {
                    C[row * N + col] = f2bf(v);
                    ps += v; pq += v * v;
                }
            }
            if (do_stats) {
                atomicAdd(&s_sum[colL], ps);
                atomicAdd(&s_sq[colL], pq);
            }
        }
    }
    if (do_stats) {
        __syncthreads();
        if (tid < 128) {
            atomicAdd(&gsums[colBase + tid], s_sum[tid]);
            atomicAdd(&gsqs[colBase + tid], s_sq[tid]);
        }
    }
}

// ======== BN params ========
__global__ void bnparam_kernel(const float* __restrict__ sums, const float* __restrict__ sqs,
                               const float* __restrict__ gamma, const float* __restrict__ beta,
                               float* __restrict__ scale, float* __restrict__ shift,
                               int N, float invM)
{
    int c = blockIdx.x * blockDim.x + threadIdx.x;
    if (c < N) {
        float mean = sums[c] * invM;
        float var = sqs[c] * invM - mean * mean;
        float sc = gamma[c] * rsqrtf(var + BN_EPS);
        scale[c] = sc;
        shift[c] = beta[c] - mean * sc;
    }
}

// ======== BN + act, bf16 -> bf16 (x4 vector), input contiguous, output strided ========
__global__ __launch_bounds__(256) void bnact_bf16(
    const ushort* __restrict__ X, const float* __restrict__ scale, const float* __restrict__ shift,
    ushort* __restrict__ O, int total4, int logN, int outStride, float negSlope)
{
    int stride = gridDim.x * blockDim.x;
    int Nm1 = (1 << logN) - 1;
    for (int t = blockIdx.x * blockDim.x + threadIdx.x; t < total4; t += stride) {
        int idx = t * 4;
        int row = idx >> logN;
        int c = idx & Nm1;
        ushort4 v4 = *(const ushort4*)&X[idx];
        float4 sc = *(const float4*)&scale[c];
        float4 sh = *(const float4*)&shift[c];
        float a = bf2f(v4.x) * sc.x + sh.x; a = (a > 0.f) ? a : a * negSlope;
        float b = bf2f(v4.y) * sc.y + sh.y; b = (b > 0.f) ? b : b * negSlope;
        float d = bf2f(v4.z) * sc.z + sh.z; d = (d > 0.f) ? d : d * negSlope;
        float e = bf2f(v4.w) * sc.w + sh.w; e = (e > 0.f) ? e : e * negSlope;
        ushort4 o; o.x = f2bf(a); o.y = f2bf(b); o.z = f2bf(d); o.w = f2bf(e);
        *(ushort4*)&O[(long)row * outStride + c] = o;
    }
}

// ======== BN + act, fp32 in-place (final output) ========
__global__ __launch_bounds__(256) void bnact_f32(
    float* __restrict__ X, const float* __restrict__ scale, const float* __restrict__ shift,
    int total4, int logN, float negSlope)
{
    int stride = gridDim.x * blockDim.x;
    int Nm1 = (1 << logN) - 1;
    for (int t = blockIdx.x * blockDim.x + threadIdx.x; t < total4; t += stride) {
        int idx = t * 4;
        int c = idx & Nm1;
        float4 v = *(const float4*)&X[idx];
        float4 sc = *(const float4*)&scale[c];
        float4 sh = *(const float4*)&shift[c];
        float a = v.x * sc.x + sh.x; a = (a > 0.f) ? a : a * negSlope;
        float b = v.y * sc.y + sh.y; b = (b > 0.f) ? b : b * negSlope;
        float d = v.z * sc.z + sh.z; d = (d > 0.f) ? d : d * negSlope;
        float e = v.w * sc.w + sh.w; e = (e > 0.f) ? e : e * negSlope;
        *(float4*)&X[idx] = make_float4(a, b, d, e);
    }
}

// ======== column stats for final output (128 cols, register accum) ========
__global__ __launch_bounds__(256) void colstats128(
    const float* __restrict__ X, float* __restrict__ sums, float* __restrict__ sqs, int M)
{
    __shared__ float ss[128], sq[128];
    int tid = threadIdx.x;
    if (tid < 128) { ss[tid] = 0.f; sq[tid] = 0.f; }
    __syncthreads();
    int cg = tid & 31;
    int worker = (blockIdx.x << 3) | (tid >> 5);
    int totalW = gridDim.x << 3;
    float4 s4 = make_float4(0, 0, 0, 0), q4 = make_float4(0, 0, 0, 0);
    for (int r = worker; r < M; r += totalW) {
        float4 v = *(const float4*)&X[(long)r * 128 + cg * 4];
        s4.x += v.x; s4.y += v.y; s4.z += v.z; s4.w += v.w;
        q4.x += v.x * v.x; q4.y += v.y * v.y; q4.z += v.z * v.z; q4.w += v.w * v.w;
    }
    atomicAdd(&ss[cg * 4 + 0], s4.x); atomicAdd(&sq[cg * 4 + 0], q4.x);
    atomicAdd(&ss[cg * 4 + 1], s4.y); atomicAdd(&sq[cg * 4 + 1], q4.y);
    atomicAdd(&ss[cg * 4 + 2], s4.z); atomicAdd(&sq[cg * 4 + 2], q4.z);
    atomicAdd(&ss[cg * 4 + 3], s4.w); atomicAdd(&sq[cg * 4 + 3], q4.w);
    __syncthreads();
    if (tid < 128) { atomicAdd(&sums[tid], ss[tid]); atomicAdd(&sqs[tid], sq[tid]); }
}

// ======== converts ========
__global__ void convert_nodes(const float* __restrict__ X, ushort* __restrict__ O, int total4)
{
    int t = blockIdx.x * blockDim.x + threadIdx.x;
    if (t < total4) {
        float4 v = *(const float4*)&X[t * 4];
        ushort4 o; o.x = f2bf(v.x); o.y = f2bf(v.y); o.z = f2bf(v.z); o.w = f2bf(v.w);
        *(ushort4*)&O[t * 4] = o;
    }
}

// all six weight transposes in one kernel; seg = blockIdx.y
// WT[dstBase + n*stride + kOff + k] = bf16(W[k*N + n]),  N = 32768>>logK
__global__ void wt_all(const float* __restrict__ W0, const float* __restrict__ W1,
                       const float* __restrict__ W2, const float* __restrict__ W3,
                       const float* __restrict__ W4, const float* __restrict__ W5,
                       ushort* __restrict__ WT)
{
    int seg = blockIdx.y;
    const float* W; int logK, dstBase, stride, kOff;
    switch (seg) {
        case 0: W = W0; logK = 7; dstBase = 0;      stride = 128; kOff = 0;   break;
        case 1: W = W1; logK = 8; dstBase = 32768;  stride = 256; kOff = 0;   break;
        case 2: W = W2; logK = 7; dstBase = 65536;  stride = 256; kOff = 0;   break;
        case 3: W = W3; logK = 7; dstBase = 65536;  stride = 256; kOff = 128; break;
        case 4: W = W4; logK = 8; dstBase = 131072; stride = 256; kOff = 0;   break;
        default:W = W5; logK = 8; dstBase = 163840; stride = 256; kOff = 0;   break;
    }
    int t = blockIdx.x * blockDim.x + threadIdx.x;
    int N = 32768 >> logK;
    int k = t & ((1 << logK) - 1);
    int n = t >> logK;
    WT[(long)dstBase + (long)n * stride + kOff + k] = f2bf(W[(long)k * N + n]);
}

// ======== CSR build ========
__global__ void degcount_kernel(const int* __restrict__ dst, int* __restrict__ degi, int E)
{
    int i = blockIdx.x * blockDim.x + threadIdx.x;
    if (i < E) atomicAdd(&degi[dst[i]], 1);
}

__global__ __launch_bounds__(256) void scan_block_sums(const int* __restrict__ degi,
                                                       int* __restrict__ partial, int n)
{
    __shared__ int s[256];
    int i = blockIdx.x * 256 + threadIdx.x;
    s[threadIdx.x] = (i < n) ? degi[i] : 0;
    __syncthreads();
    for (int off = 128; off > 0; off >>= 1) {
        if (threadIdx.x < off) s[threadIdx.x] += s[threadIdx.x + off];
        __syncthreads();
    }
    if (threadIdx.x == 0) partial[blockIdx.x] = s[0];
}

__global__ __launch_bounds__(256) void scan_partials(int* __restrict__ partial, int nb)
{
    __shared__ int s[256];
    int v = (threadIdx.x < nb) ? partial[threadIdx.x] : 0;
    s[threadIdx.x] = v;
    __syncthreads();
    for (int off = 1; off < 256; off <<= 1) {
        int t = (threadIdx.x >= off) ? s[threadIdx.x - off] : 0;
        __syncthreads();
        s[threadIdx.x] += t;
        __syncthreads();
    }
    if (threadIdx.x < nb) partial[threadIdx.x] = s[threadIdx.x] - v;
}

__global__ __launch_bounds__(256) void scan_final(const int* __restrict__ degi,
                                                  const int* __restrict__ partial,
                                                  int* __restrict__ rowstart, int n)
{
    __shared__ int s[256];
    int i = blockIdx.x * 256 + threadIdx.x;
    int v = (i < n) ? degi[i] : 0;
    s[threadIdx.x] = v;
    __syncthreads();
    for (int off = 1; off < 256; off <<= 1) {
        int t = (threadIdx.x >= off) ? s[threadIdx.x - off] : 0;
        __syncthreads();
        s[threadIdx.x] += t;
        __syncthreads();
    }
    if (i < n) rowstart[i] = partial[blockIdx.x] + s[threadIdx.x] - v;
}

__global__ void fillcsr_kernel(const int* __restrict__ src, const int* __restrict__ dst,
                               const int* __restrict__ rowstart, int* __restrict__ cursor,
                               int* __restrict__ csr, int E)
{
    int i = blockIdx.x * blockDim.x + threadIdx.x;
    if (i < E) {
        int d = dst[i];
        int p = atomicAdd(&cursor[d], 1);
        csr[rowstart[d] + p] = src[i];
    }
}

// ======== gather mean (bf16 in/out), one wave per node, 128 cols, stride 256 ========
__global__ __launch_bounds__(256) void gather_bf(
    const ushort* __restrict__ X, const int* __restrict__ rowstart,
    const int* __restrict__ degi, const int* __restrict__ csr,
    ushort* __restrict__ O, int nN)
{
    int wv = (blockIdx.x * blockDim.x + threadIdx.x) >> 6;
    int lane = threadIdx.x & 63;
    if (wv >= nN) return;
    int start = rowstart[wv], d = degi[wv];
    float a0 = 0.f, a1 = 0.f;
    int col = lane * 2;
    for (int j = 0; j < d; j++) {
        int s = csr[start + j];
        unsigned pv = *(const unsigned*)(X + (long)s * 256 + col);
        a0 += bf2f((ushort)(pv & 0xffff));
        a1 += bf2f((ushort)(pv >> 16));
    }
    float inv = 1.f / fmaxf((float)d, 1.f);
    unsigned o = (unsigned)f2bf(a0 * inv) | ((unsigned)f2bf(a1 * inv) << 16);
    *(unsigned*)(O + (long)wv * 256 + col) = o;
}

// ======== fused gather2: out = mean(Z[src, 0:128]) + Z[dst, 128:256]  (fp32 out) ========
__global__ __launch_bounds__(256) void gather_fuse(
    const ushort* __restrict__ Z, const int* __restrict__ rowstart,
    const int* __restrict__ degi, const int* __restrict__ csr,
    float* __restrict__ O, int nN)
{
    int wv = (blockIdx.x * blockDim.x + threadIdx.x) >> 6;
    int lane = threadIdx.x & 63;
    if (wv >= nN) return;
    int start = rowstart[wv], d = degi[wv];
    float a0 = 0.f, a1 = 0.f;
    int col = lane * 2;
    for (int j = 0; j < d; j++) {
        int s = csr[start + j];
        unsigned pv = *(const unsigned*)(Z + (long)s * 256 + col);
        a0 += bf2f((ushort)(pv & 0xffff));
        a1 += bf2f((ushort)(pv >> 16));
    }
    float inv = 1.f / fmaxf((float)d, 1.f);
    unsigned sv = *(const unsigned*)(Z + (long)wv * 256 + 128 + col);
    float s0 = bf2f((ushort)(sv & 0xffff));
    float s1 = bf2f((ushort)(sv >> 16));
    *(float2*)(O + (long)wv * 128 + col) = make_float2(a0 * inv + s0, a1 * inv + s1);
}

extern "C" void kernel_launch(void* const* d_in, const int* in_sizes, int n_in,
                              void* d_out, int out_size, void* d_ws, size_t ws_size,
                              hipStream_t stream)
{
    const float* nodes = (const float*)d_in[0];
    const int*   src   = (const int*)d_in[1];
    const int*   dst   = (const int*)d_in[2];
    const float* Wf1   = (const float*)d_in[3];
    const float* gf1   = (const float*)d_in[5];
    const float* bef1  = (const float*)d_in[6];
    const float* Wf2   = (const float*)d_in[7];
    const float* gf2   = (const float*)d_in[9];
    const float* bef2  = (const float*)d_in[10];
    const float* Ws1   = (const float*)d_in[11];
    const float* Wn1   = (const float*)d_in[12];
    const float* gs1   = (const float*)d_in[14];
    const float* bs1   = (const float*)d_in[15];
    const float* Ws2   = (const float*)d_in[16];
    const float* Wn2   = (const float*)d_in[17];
    const float* gs2   = (const float*)d_in[19];
    const float* bs2   = (const float*)d_in[20];
    // pre-BN biases (bf1,bf2,b1,b2) cancel under BatchNorm -> skipped

    int nN = in_sizes[0] / DIN;   // 50000
    int nE = in_sizes[1];         // 600000
    float* out = (float*)d_out;

    // ---- workspace ----
    ushort* PRE = (ushort*)d_ws;                      // nN*256 bf16 pre-BN GEMM out
    ushort* BF1 = PRE + (size_t)nN * 256;             // nN*256 bf16 (Xn / X1 / h1)
    ushort* BF2 = BF1 + (size_t)nN * 256;             // nN*256 bf16 ([h|agg] / Z)
    float* stats = (float*)(BF2 + (size_t)nN * 256);  // 2048 floats, 4 layer-regions
    float* scale = stats + 2048;                      // 256
    float* shift = scale + 256;                       // 256
    ushort* WT   = (ushort*)(shift + 256);            // 196608 shorts
    int* degi     = (int*)(WT + 196608);              // nN
    int* cursor   = degi + nN;                        // nN (adjacent to degi: one memset)
    int* rowstart = cursor + nN;                      // nN
    int* partial  = rowstart + nN;                    // 256
    int* csr      = partial + 256;                    // nE

    ushort* Wf1T = WT;
    ushort* Wf2T = WT + 32768;
    ushort* Wc1T = WT + 65536;
    ushort* Wc2T = WT + 131072;

    dim3 blk(256);
    auto cdiv = [](int a, int b) { return (a + b - 1) / b; };
    int gM = cdiv(nN, 128);           // 391
    int nScanBlocks = cdiv(nN, 256);

    // ---- converts + zero-init (batched) ----
    convert_nodes<<<dim3(cdiv(nN * DIN / 4, 256)), blk, 0, stream>>>(nodes, BF1, nN * DIN / 4);
    wt_all<<<dim3(128, 6), blk, 0, stream>>>(Wf1, Wf2, Ws1, Wn1, Wn2, Ws2, WT);
    hipMemsetAsync(stats, 0, 2048 * sizeof(float), stream);
    hipMemsetAsync(degi, 0, 2 * (size_t)nN * sizeof(int), stream);

    // ---- CSR build ----
    degcount_kernel<<<dim3(cdiv(nE, 256)), blk, 0, stream>>>(dst, degi, nE);
    scan_block_sums<<<dim3(nScanBlocks), blk, 0, stream>>>(degi, partial, nN);
    scan_partials<<<dim3(1), blk, 0, stream>>>(partial, nScanBlocks);
    scan_final<<<dim3(nScanBlocks), blk, 0, stream>>>(degi, partial, rowstart, nN);
    fillcsr_kernel<<<dim3(cdiv(nE, 256)), blk, 0, stream>>>(src, dst, rowstart, cursor, csr, nE);

    // ---- FF1: PRE = Xn @ Wf1T (K=128, stats->L0) ; BN+ReLU -> BF1 ----
    mfma_gemm<<<dim3(gM, 2), blk, 0, stream>>>(BF1, Wf1T, PRE, nN, 256, 128, 1, stats, stats + 256);
    bnparam_kernel<<<dim3(1), blk, 0, stream>>>(stats, stats + 256, gf1, bef1, scale, shift, 256, 1.0f / nN);
    bnact_bf16<<<dim3(2048), blk, 0, stream>>>(PRE, scale, shift, BF1, nN * 256 / 4, 8, 256, 0.0f);

    // ---- FF2: PRE = BF1 @ Wf2T (K=256, N=128, stats->L1) ; BN+ReLU -> BF2[:,0:128] ----
    mfma_gemm<<<dim3(gM, 1), blk, 0, stream>>>(BF1, Wf2T, PRE, nN, 128, 256, 1, stats + 512, stats + 768);
    bnparam_kernel<<<dim3(1), blk, 0, stream>>>(stats + 512, stats + 768, gf2, bef2, scale, shift, 128, 1.0f / nN);
    bnact_bf16<<<dim3(2048), blk, 0, stream>>>(PRE, scale, shift, BF2, nN * 128 / 4, 7, 256, 0.0f);

    // ---- gather1: BF2[:,128:256] = mean-gather(BF2[:,0:128]) ----
    gather_bf<<<dim3(cdiv(nN * 64, 256)), blk, 0, stream>>>(BF2, rowstart, degi, csr, BF2 + 128, nN);

    // ---- SAGE1: PRE = [h|agg] @ [Ws1;Wn1] (K=256, stats->L2) ; BN+LReLU -> BF1 (h1) ----
    mfma_gemm<<<dim3(gM, 2), blk, 0, stream>>>(BF2, Wc1T, PRE, nN, 256, 256, 1, stats + 1024, stats + 1280);
    bnparam_kernel<<<dim3(1), blk, 0, stream>>>(stats + 1024, stats + 1280, gs1, bs1, scale, shift, 256, 1.0f / nN);
    bnact_bf16<<<dim3(2048), blk, 0, stream>>>(PRE, scale, shift, BF1, nN * 256 / 4, 8, 256, 0.01f);

    // ---- SAGE2: BF2 = h1 @ [Wn2|Ws2] (no stats) ; gather_fuse -> out(fp32) ----
    mfma_gemm<<<dim3(gM, 2), blk, 0, stream>>>(BF1, Wc2T, BF2, nN, 256, 256, 0, nullptr, nullptr);
    gather_fuse<<<dim3(cdiv(nN * 64, 256)), blk, 0, stream>>>(BF2, rowstart, degi, csr, out, nN);

    // ---- final BN+LReLU on out (stats->L3) ----
    colstats128<<<dim3(120), blk, 0, stream>>>(out, stats + 1536, stats + 1792, nN);
    bnparam_kernel<<<dim3(1), blk, 0, stream>>>(stats + 1536, stats + 1792, gs2, bs2, scale, shift, 128, 1.0f / nN);
    bnact_f32<<<dim3(2048), blk, 0, stream>>>(out, scale, shift, nN * 128 / 4, 7, 0.01f);
}

// Round 6
// 435.970 us; speedup vs baseline: 3.9004x; 1.2734x over previous
//
#include <hip/hip_runtime.h>

#define DIN 128
#define BN_EPS 1e-5f

typedef __attribute__((ext_vector_type(8))) short bf16x8;
typedef __attribute__((ext_vector_type(4))) float f32x4;
typedef unsigned int u32;

__device__ __forceinline__ ushort f2bf(float f) {
    unsigned u = __float_as_uint(f);
    u += 0x7fffu + ((u >> 16) & 1u);
    return (ushort)(u >> 16);
}
__device__ __forceinline__ float bf2f(ushort h) {
    return __uint_as_float(((unsigned)h) << 16);
}

// ======== barrier-free streaming GEMM: C[M,N](bf16) = A[M,K](bf16) @ BT[N,K]^T ========
// Each wave owns a 64-col group: B-frags live in registers (loaded once, L2-hit).
// Streams 16-row A-strips: 8 independent 16B loads + 32 MFMAs, no LDS, no syncs.
// Column stats accumulate in registers across strips; shfl-reduced at the end.
template<int KC, int STATS>
__global__ __launch_bounds__(256) void gemm_wreg(
    const ushort* __restrict__ A, const ushort* __restrict__ BT,
    ushort* __restrict__ C, int mStrips, int N, int K, int logNG,
    float* __restrict__ gsums, float* __restrict__ gsqs)
{
    int tid = threadIdx.x;
    int lane = tid & 63;
    int gw = blockIdx.x * 4 + (tid >> 6);
    int wg = gw & ((1 << logNG) - 1);
    int set = gw >> logNG;
    int totalSets = (gridDim.x * 4) >> logNG;
    int cl = lane & 15, q = lane >> 4;
    int colBase = wg * 64;

    // B fragments: [ntile][kchunk], A-operand layout: elem (n=cl, k=kc*32+q*8+j)
    bf16x8 bf[4][KC];
    #pragma unroll
    for (int nt = 0; nt < 4; nt++) {
        const ushort* bp = BT + (long)(colBase + nt * 16 + cl) * K + q * 8;
        #pragma unroll
        for (int kc = 0; kc < KC; kc++)
            bf[nt][kc] = *(const bf16x8*)(bp + kc * 32);
    }

    float ssum[4] = {0.f, 0.f, 0.f, 0.f};
    float ssq[4]  = {0.f, 0.f, 0.f, 0.f};

    for (int strip = set; strip < mStrips; strip += totalSets) {
        int rowBase = strip * 16;
        const ushort* ap = A + (long)(rowBase + cl) * K + q * 8;
        bf16x8 af[KC];
        #pragma unroll
        for (int kc = 0; kc < KC; kc++)
            af[kc] = *(const bf16x8*)(ap + kc * 32);
        f32x4 acc[4] = {};
        #pragma unroll
        for (int kc = 0; kc < KC; kc++)
            #pragma unroll
            for (int nt = 0; nt < 4; nt++)
                acc[nt] = __builtin_amdgcn_mfma_f32_16x16x32_bf16(af[kc], bf[nt][kc], acc[nt], 0, 0, 0);
        // C/D layout: col=lane&15, row=q*4+r
        #pragma unroll
        for (int nt = 0; nt < 4; nt++) {
            #pragma unroll
            for (int r = 0; r < 4; r++) {
                float v = acc[nt][r];
                long row = rowBase + q * 4 + r;
                C[row * N + colBase + nt * 16 + cl] = f2bf(v);
                if (STATS) { ssum[nt] += v; ssq[nt] += v * v; }
            }
        }
    }

    if (STATS) {
        #pragma unroll
        for (int nt = 0; nt < 4; nt++) {
            ssum[nt] += __shfl_xor(ssum[nt], 16, 64);
            ssum[nt] += __shfl_xor(ssum[nt], 32, 64);
            ssq[nt]  += __shfl_xor(ssq[nt], 16, 64);
            ssq[nt]  += __shfl_xor(ssq[nt], 32, 64);
        }
        if (q == 0) {
            #pragma unroll
            for (int nt = 0; nt < 4; nt++) {
                atomicAdd(&gsums[colBase + nt * 16 + cl], ssum[nt]);
                atomicAdd(&gsqs[colBase + nt * 16 + cl], ssq[nt]);
            }
        }
    }
}

// ======== BN params ========
__global__ void bnparam_kernel(const float* __restrict__ sums, const float* __restrict__ sqs,
                               const float* __restrict__ gamma, const float* __restrict__ beta,
                               float* __restrict__ scale, float* __restrict__ shift,
                               int N, float invM)
{
    int c = blockIdx.x * blockDim.x + threadIdx.x;
    if (c < N) {
        float mean = sums[c] * invM;
        float var = sqs[c] * invM - mean * mean;
        float sc = gamma[c] * rsqrtf(var + BN_EPS);
        scale[c] = sc;
        shift[c] = beta[c] - mean * sc;
    }
}

// ======== BN + act, bf16 -> bf16 (x4 vector), input contiguous, output strided ========
__global__ __launch_bounds__(256) void bnact_bf16(
    const ushort* __restrict__ X, const float* __restrict__ scale, const float* __restrict__ shift,
    ushort* __restrict__ O, int total4, int logN, int outStride, float negSlope)
{
    int stride = gridDim.x * blockDim.x;
    int Nm1 = (1 << logN) - 1;
    for (int t = blockIdx.x * blockDim.x + threadIdx.x; t < total4; t += stride) {
        int idx = t * 4;
        int row = idx >> logN;
        int c = idx & Nm1;
        ushort4 v4 = *(const ushort4*)&X[idx];
        float4 sc = *(const float4*)&scale[c];
        float4 sh = *(const float4*)&shift[c];
        float a = bf2f(v4.x) * sc.x + sh.x; a = (a > 0.f) ? a : a * negSlope;
        float b = bf2f(v4.y) * sc.y + sh.y; b = (b > 0.f) ? b : b * negSlope;
        float d = bf2f(v4.z) * sc.z + sh.z; d = (d > 0.f) ? d : d * negSlope;
        float e = bf2f(v4.w) * sc.w + sh.w; e = (e > 0.f) ? e : e * negSlope;
        ushort4 o; o.x = f2bf(a); o.y = f2bf(b); o.z = f2bf(d); o.w = f2bf(e);
        *(ushort4*)&O[(long)row * outStride + c] = o;
    }
}

// ======== BN + act, fp32 in-place (final output) ========
__global__ __launch_bounds__(256) void bnact_f32(
    float* __restrict__ X, const float* __restrict__ scale, const float* __restrict__ shift,
    int total4, int logN, float negSlope)
{
    int stride = gridDim.x * blockDim.x;
    int Nm1 = (1 << logN) - 1;
    for (int t = blockIdx.x * blockDim.x + threadIdx.x; t < total4; t += stride) {
        int idx = t * 4;
        int c = idx & Nm1;
        float4 v = *(const float4*)&X[idx];
        float4 sc = *(const float4*)&scale[c];
        float4 sh = *(const float4*)&shift[c];
        float a = v.x * sc.x + sh.x; a = (a > 0.f) ? a : a * negSlope;
        float b = v.y * sc.y + sh.y; b = (b > 0.f) ? b : b * negSlope;
        float d = v.z * sc.z + sh.z; d = (d > 0.f) ? d : d * negSlope;
        float e = v.w * sc.w + sh.w; e = (e > 0.f) ? e : e * negSlope;
        *(float4*)&X[idx] = make_float4(a, b, d, e);
    }
}

// ======== column stats for final output (128 cols, register accum) ========
__global__ __launch_bounds__(256) void colstats128(
    const float* __restrict__ X, float* __restrict__ sums, float* __restrict__ sqs, int M)
{
    __shared__ float ss[128], sq[128];
    int tid = threadIdx.x;
    if (tid < 128) { ss[tid] = 0.f; sq[tid] = 0.f; }
    __syncthreads();
    int cg = tid & 31;
    int worker = (blockIdx.x << 3) | (tid >> 5);
    int totalW = gridDim.x << 3;
    float4 s4 = make_float4(0, 0, 0, 0), q4 = make_float4(0, 0, 0, 0);
    for (int r = worker; r < M; r += totalW) {
        float4 v = *(const float4*)&X[(long)r * 128 + cg * 4];
        s4.x += v.x; s4.y += v.y; s4.z += v.z; s4.w += v.w;
        q4.x += v.x * v.x; q4.y += v.y * v.y; q4.z += v.z * v.z; q4.w += v.w * v.w;
    }
    atomicAdd(&ss[cg * 4 + 0], s4.x); atomicAdd(&sq[cg * 4 + 0], q4.x);
    atomicAdd(&ss[cg * 4 + 1], s4.y); atomicAdd(&sq[cg * 4 + 1], q4.y);
    atomicAdd(&ss[cg * 4 + 2], s4.z); atomicAdd(&sq[cg * 4 + 2], q4.z);
    atomicAdd(&ss[cg * 4 + 3], s4.w); atomicAdd(&sq[cg * 4 + 3], q4.w);
    __syncthreads();
    if (tid < 128) { atomicAdd(&sums[tid], ss[tid]); atomicAdd(&sqs[tid], sq[tid]); }
}

// ======== converts ========
__global__ void convert_nodes(const float* __restrict__ X, ushort* __restrict__ O, int total4)
{
    int t = blockIdx.x * blockDim.x + threadIdx.x;
    if (t < total4) {
        float4 v = *(const float4*)&X[t * 4];
        ushort4 o; o.x = f2bf(v.x); o.y = f2bf(v.y); o.z = f2bf(v.z); o.w = f2bf(v.w);
        *(ushort4*)&O[t * 4] = o;
    }
}

// all six weight transposes in one kernel; seg = blockIdx.y
__global__ void wt_all(const float* __restrict__ W0, const float* __restrict__ W1,
                       const float* __restrict__ W2, const float* __restrict__ W3,
                       const float* __restrict__ W4, const float* __restrict__ W5,
                       ushort* __restrict__ WT)
{
    int seg = blockIdx.y;
    const float* W; int logK, dstBase, stride, kOff;
    switch (seg) {
        case 0: W = W0; logK = 7; dstBase = 0;      stride = 128; kOff = 0;   break;
        case 1: W = W1; logK = 8; dstBase = 32768;  stride = 256; kOff = 0;   break;
        case 2: W = W2; logK = 7; dstBase = 65536;  stride = 256; kOff = 0;   break;
        case 3: W = W3; logK = 7; dstBase = 65536;  stride = 256; kOff = 128; break;
        case 4: W = W4; logK = 8; dstBase = 131072; stride = 256; kOff = 0;   break;
        default:W = W5; logK = 8; dstBase = 163840; stride = 256; kOff = 0;   break;
    }
    int t = blockIdx.x * blockDim.x + threadIdx.x;
    int N = 32768 >> logK;
    int k = t & ((1 << logK) - 1);
    int n = t >> logK;
    WT[(long)dstBase + (long)n * stride + kOff + k] = f2bf(W[(long)k * N + n]);
}

// ======== CSR build ========
__global__ void degcount_kernel(const int* __restrict__ dst, int* __restrict__ degi, int E)
{
    int i = blockIdx.x * blockDim.x + threadIdx.x;
    if (i < E) atomicAdd(&degi[dst[i]], 1);
}

__global__ __launch_bounds__(256) void scan_block_sums(const int* __restrict__ degi,
                                                       int* __restrict__ partial, int n)
{
    __shared__ int s[256];
    int i = blockIdx.x * 256 + threadIdx.x;
    s[threadIdx.x] = (i < n) ? degi[i] : 0;
    __syncthreads();
    for (int off = 128; off > 0; off >>= 1) {
        if (threadIdx.x < off) s[threadIdx.x] += s[threadIdx.x + off];
        __syncthreads();
    }
    if (threadIdx.x == 0) partial[blockIdx.x] = s[0];
}

__global__ __launch_bounds__(256) void scan_partials(int* __restrict__ partial, int nb)
{
    __shared__ int s[256];
    int v = (threadIdx.x < nb) ? partial[threadIdx.x] : 0;
    s[threadIdx.x] = v;
    __syncthreads();
    for (int off = 1; off < 256; off <<= 1) {
        int t = (threadIdx.x >= off) ? s[threadIdx.x - off] : 0;
        __syncthreads();
        s[threadIdx.x] += t;
        __syncthreads();
    }
    if (threadIdx.x < nb) partial[threadIdx.x] = s[threadIdx.x] - v;
}

__global__ __launch_bounds__(256) void scan_final(const int* __restrict__ degi,
                                                  const int* __restrict__ partial,
                                                  int* __restrict__ rowstart, int n)
{
    __shared__ int s[256];
    int i = blockIdx.x * 256 + threadIdx.x;
    int v = (i < n) ? degi[i] : 0;
    s[threadIdx.x] = v;
    __syncthreads();
    for (int off = 1; off < 256; off <<= 1) {
        int t = (threadIdx.x >= off) ? s[threadIdx.x - off] : 0;
        __syncthreads();
        s[threadIdx.x] += t;
        __syncthreads();
    }
    if (i < n) rowstart[i] = partial[blockIdx.x] + s[threadIdx.x] - v;
}

__global__ void fillcsr_kernel(const int* __restrict__ src, const int* __restrict__ dst,
                               const int* __restrict__ rowstart, int* __restrict__ cursor,
                               int* __restrict__ csr, int E)
{
    int i = blockIdx.x * blockDim.x + threadIdx.x;
    if (i < E) {
        int d = dst[i];
        int p = atomicAdd(&cursor[d], 1);
        csr[rowstart[d] + p] = src[i];
    }
}

// ======== gather mean (bf16 in/out), one wave per node, 128 cols, stride 256 ========
__global__ __launch_bounds__(256) void gather_bf(
    const ushort* __restrict__ X, const int* __restrict__ rowstart,
    const int* __restrict__ degi, const int* __restrict__ csr,
    ushort* __restrict__ O, int nN)
{
    int wv = (blockIdx.x * blockDim.x + threadIdx.x) >> 6;
    int lane = threadIdx.x & 63;
    if (wv >= nN) return;
    int start = rowstart[wv], d = degi[wv];
    float a0 = 0.f, a1 = 0.f;
    int col = lane * 2;
    int j = 0;
    for (; j + 2 <= d; j += 2) {
        int s0 = csr[start + j];
        int s1 = csr[start + j + 1];
        unsigned p0 = *(const unsigned*)(X + (long)s0 * 256 + col);
        unsigned p1 = *(const unsigned*)(X + (long)s1 * 256 + col);
        a0 += bf2f((ushort)(p0 & 0xffff)) + bf2f((ushort)(p1 & 0xffff));
        a1 += bf2f((ushort)(p0 >> 16)) + bf2f((ushort)(p1 >> 16));
    }
    if (j < d) {
        int s0 = csr[start + j];
        unsigned p0 = *(const unsigned*)(X + (long)s0 * 256 + col);
        a0 += bf2f((ushort)(p0 & 0xffff));
        a1 += bf2f((ushort)(p0 >> 16));
    }
    float inv = 1.f / fmaxf((float)d, 1.f);
    unsigned o = (unsigned)f2bf(a0 * inv) | ((unsigned)f2bf(a1 * inv) << 16);
    *(unsigned*)(O + (long)wv * 256 + col) = o;
}

// ======== fused gather2: out = mean(Z[src, 0:128]) + Z[dst, 128:256]  (fp32 out) ========
__global__ __launch_bounds__(256) void gather_fuse(
    const ushort* __restrict__ Z, const int* __restrict__ rowstart,
    const int* __restrict__ degi, const int* __restrict__ csr,
    float* __restrict__ O, int nN)
{
    int wv = (blockIdx.x * blockDim.x + threadIdx.x) >> 6;
    int lane = threadIdx.x & 63;
    if (wv >= nN) return;
    int start = rowstart[wv], d = degi[wv];
    float a0 = 0.f, a1 = 0.f;
    int col = lane * 2;
    int j = 0;
    for (; j + 2 <= d; j += 2) {
        int s0 = csr[start + j];
        int s1 = csr[start + j + 1];
        unsigned p0 = *(const unsigned*)(Z + (long)s0 * 256 + col);
        unsigned p1 = *(const unsigned*)(Z + (long)s1 * 256 + col);
        a0 += bf2f((ushort)(p0 & 0xffff)) + bf2f((ushort)(p1 & 0xffff));
        a1 += bf2f((ushort)(p0 >> 16)) + bf2f((ushort)(p1 >> 16));
    }
    if (j < d) {
        int s0 = csr[start + j];
        unsigned p0 = *(const unsigned*)(Z + (long)s0 * 256 + col);
        a0 += bf2f((ushort)(p0 & 0xffff));
        a1 += bf2f((ushort)(p0 >> 16));
    }
    float inv = 1.f / fmaxf((float)d, 1.f);
    unsigned sv = *(const unsigned*)(Z + (long)wv * 256 + 128 + col);
    float s0 = bf2f((ushort)(sv & 0xffff));
    float s1 = bf2f((ushort)(sv >> 16));
    *(float2*)(O + (long)wv * 128 + col) = make_float2(a0 * inv + s0, a1 * inv + s1);
}

extern "C" void kernel_launch(void* const* d_in, const int* in_sizes, int n_in,
                              void* d_out, int out_size, void* d_ws, size_t ws_size,
                              hipStream_t stream)
{
    const float* nodes = (const float*)d_in[0];
    const int*   src   = (const int*)d_in[1];
    const int*   dst   = (const int*)d_in[2];
    const float* Wf1   = (const float*)d_in[3];
    const float* gf1   = (const float*)d_in[5];
    const float* bef1  = (const float*)d_in[6];
    const float* Wf2   = (const float*)d_in[7];
    const float* gf2   = (const float*)d_in[9];
    const float* bef2  = (const float*)d_in[10];
    const float* Ws1   = (const float*)d_in[11];
    const float* Wn1   = (const float*)d_in[12];
    const float* gs1   = (const float*)d_in[14];
    const float* bs1   = (const float*)d_in[15];
    const float* Ws2   = (const float*)d_in[16];
    const float* Wn2   = (const float*)d_in[17];
    const float* gs2   = (const float*)d_in[19];
    const float* bs2   = (const float*)d_in[20];
    // pre-BN biases (bf1,bf2,b1,b2) cancel under BatchNorm -> skipped

    int nN = in_sizes[0] / DIN;   // 50000
    int nE = in_sizes[1];         // 600000
    float* out = (float*)d_out;
    int mStrips = nN / 16;        // 3125 (exact)

    // ---- workspace ----
    ushort* PRE = (ushort*)d_ws;                      // nN*256 bf16 pre-BN GEMM out
    ushort* BF1 = PRE + (size_t)nN * 256;             // nN*256 bf16 (Xn / X1 / h1)
    ushort* BF2 = BF1 + (size_t)nN * 256;             // nN*256 bf16 ([h|agg] / Z)
    float* stats = (float*)(BF2 + (size_t)nN * 256);  // 2048 floats, 4 layer-regions
    float* scale = stats + 2048;                      // 256
    float* shift = scale + 256;                       // 256
    ushort* WT   = (ushort*)(shift + 256);            // 196608 shorts
    int* degi     = (int*)(WT + 196608);              // nN
    int* cursor   = degi + nN;                        // nN (adjacent: one memset)
    int* rowstart = cursor + nN;                      // nN
    int* partial  = rowstart + nN;                    // 256
    int* csr      = partial + 256;                    // nE

    ushort* Wf1T = WT;
    ushort* Wf2T = WT + 32768;
    ushort* Wc1T = WT + 65536;
    ushort* Wc2T = WT + 131072;

    dim3 blk(256);
    auto cdiv = [](int a, int b) { return (a + b - 1) / b; };
    int nScanBlocks = cdiv(nN, 256);

    // ---- converts + zero-init ----
    convert_nodes<<<dim3(cdiv(nN * DIN / 4, 256)), blk, 0, stream>>>(nodes, BF1, nN * DIN / 4);
    wt_all<<<dim3(128, 6), blk, 0, stream>>>(Wf1, Wf2, Ws1, Wn1, Wn2, Ws2, WT);
    hipMemsetAsync(stats, 0, 2048 * sizeof(float), stream);
    hipMemsetAsync(degi, 0, 2 * (size_t)nN * sizeof(int), stream);

    // ---- CSR build ----
    degcount_kernel<<<dim3(cdiv(nE, 256)), blk, 0, stream>>>(dst, degi, nE);
    scan_block_sums<<<dim3(nScanBlocks), blk, 0, stream>>>(degi, partial, nN);
    scan_partials<<<dim3(1), blk, 0, stream>>>(partial, nScanBlocks);
    scan_final<<<dim3(nScanBlocks), blk, 0, stream>>>(degi, partial, rowstart, nN);
    fillcsr_kernel<<<dim3(cdiv(nE, 256)), blk, 0, stream>>>(src, dst, rowstart, cursor, csr, nE);

    // ---- FF1: PRE = Xn @ Wf1T (K=128, N=256, stats->L0) ; BN+ReLU -> BF1 ----
    gemm_wreg<4, 1><<<dim3(512), blk, 0, stream>>>(BF1, Wf1T, PRE, mStrips, 256, 128, 2, stats, stats + 256);
    bnparam_kernel<<<dim3(1), blk, 0, stream>>>(stats, stats + 256, gf1, bef1, scale, shift, 256, 1.0f / nN);
    bnact_bf16<<<dim3(2048), blk, 0, stream>>>(PRE, scale, shift, BF1, nN * 256 / 4, 8, 256, 0.0f);

    // ---- FF2: PRE = BF1 @ Wf2T (K=256, N=128, stats->L1) ; BN+ReLU -> BF2[:,0:128] ----
    gemm_wreg<8, 1><<<dim3(256), blk, 0, stream>>>(BF1, Wf2T, PRE, mStrips, 128, 256, 1, stats + 512, stats + 768);
    bnparam_kernel<<<dim3(1), blk, 0, stream>>>(stats + 512, stats + 768, gf2, bef2, scale, shift, 128, 1.0f / nN);
    bnact_bf16<<<dim3(2048), blk, 0, stream>>>(PRE, scale, shift, BF2, nN * 128 / 4, 7, 256, 0.0f);

    // ---- gather1: BF2[:,128:256] = mean-gather(BF2[:,0:128]) ----
    gather_bf<<<dim3(cdiv(nN * 64, 256)), blk, 0, stream>>>(BF2, rowstart, degi, csr, BF2 + 128, nN);

    // ---- SAGE1: PRE = [h|agg] @ [Ws1;Wn1] (K=256, N=256, stats->L2) ; BN+LReLU -> BF1 (h1) ----
    gemm_wreg<8, 1><<<dim3(512), blk, 0, stream>>>(BF2, Wc1T, PRE, mStrips, 256, 256, 2, stats + 1024, stats + 1280);
    bnparam_kernel<<<dim3(1), blk, 0, stream>>>(stats + 1024, stats + 1280, gs1, bs1, scale, shift, 256, 1.0f / nN);
    bnact_bf16<<<dim3(2048), blk, 0, stream>>>(PRE, scale, shift, BF1, nN * 256 / 4, 8, 256, 0.01f);

    // ---- SAGE2: BF2 = h1 @ [Wn2|Ws2] (K=256, N=256, no stats) ; gather_fuse -> out(fp32) ----
    gemm_wreg<8, 0><<<dim3(512), blk, 0, stream>>>(BF1, Wc2T, BF2, mStrips, 256, 256, 2, nullptr, nullptr);
    gather_fuse<<<dim3(cdiv(nN * 64, 256)), blk, 0, stream>>>(BF2, rowstart, degi, csr, out, nN);

    // ---- final BN+LReLU on out (stats->L3) ----
    colstats128<<<dim3(120), blk, 0, stream>>>(out, stats + 1536, stats + 1792, nN);
    bnparam_kernel<<<dim3(1), blk, 0, stream>>>(stats + 1536, stats + 1792, gs2, bs2, scale, shift, 128, 1.0f / nN);
    bnact_f32<<<dim3(2048), blk, 0, stream>>>(out, scale, shift, nN * 128 / 4, 7, 0.01f);
}

// Round 8
// 419.838 us; speedup vs baseline: 4.0503x; 1.0384x over previous
//
#include <hip/hip_runtime.h>

#define DIN 128
#define BN_EPS 1e-5f

typedef __attribute__((ext_vector_type(8))) short bf16x8;
typedef __attribute__((ext_vector_type(4))) float f32x4;
typedef unsigned int u32;

__device__ __forceinline__ ushort f2bf(float f) {
    unsigned u = __float_as_uint(f);
    u += 0x7fffu + ((u >> 16) & 1u);
    return (ushort)(u >> 16);
}
__device__ __forceinline__ float bf2f(ushort h) {
    return __uint_as_float(((unsigned)h) << 16);
}

// ======== barrier-free streaming GEMM: C[M,N](bf16) = A[M,K](bf16) @ BT[N,K]^T ========
template<int KC, int STATS>
__global__ __launch_bounds__(256) void gemm_wreg(
    const ushort* __restrict__ A, const ushort* __restrict__ BT,
    ushort* __restrict__ C, int mStrips, int N, int K, int logNG,
    float* __restrict__ gsums, float* __restrict__ gsqs)
{
    int tid = threadIdx.x;
    int lane = tid & 63;
    int gw = blockIdx.x * 4 + (tid >> 6);
    int wg = gw & ((1 << logNG) - 1);
    int set = gw >> logNG;
    int totalSets = (gridDim.x * 4) >> logNG;
    int cl = lane & 15, q = lane >> 4;
    int colBase = wg * 64;

    bf16x8 bf[4][KC];
    #pragma unroll
    for (int nt = 0; nt < 4; nt++) {
        const ushort* bp = BT + (long)(colBase + nt * 16 + cl) * K + q * 8;
        #pragma unroll
        for (int kc = 0; kc < KC; kc++)
            bf[nt][kc] = *(const bf16x8*)(bp + kc * 32);
    }

    float ssum[4] = {0.f, 0.f, 0.f, 0.f};
    float ssq[4]  = {0.f, 0.f, 0.f, 0.f};

    for (int strip = set; strip < mStrips; strip += totalSets) {
        int rowBase = strip * 16;
        const ushort* ap = A + (long)(rowBase + cl) * K + q * 8;
        bf16x8 af[KC];
        #pragma unroll
        for (int kc = 0; kc < KC; kc++)
            af[kc] = *(const bf16x8*)(ap + kc * 32);
        f32x4 acc[4] = {};
        #pragma unroll
        for (int kc = 0; kc < KC; kc++)
            #pragma unroll
            for (int nt = 0; nt < 4; nt++)
                acc[nt] = __builtin_amdgcn_mfma_f32_16x16x32_bf16(af[kc], bf[nt][kc], acc[nt], 0, 0, 0);
        #pragma unroll
        for (int nt = 0; nt < 4; nt++) {
            #pragma unroll
            for (int r = 0; r < 4; r++) {
                float v = acc[nt][r];
                long row = rowBase + q * 4 + r;
                C[row * N + colBase + nt * 16 + cl] = f2bf(v);
                if (STATS) { ssum[nt] += v; ssq[nt] += v * v; }
            }
        }
    }

    if (STATS) {
        #pragma unroll
        for (int nt = 0; nt < 4; nt++) {
            ssum[nt] += __shfl_xor(ssum[nt], 16, 64);
            ssum[nt] += __shfl_xor(ssum[nt], 32, 64);
            ssq[nt]  += __shfl_xor(ssq[nt], 16, 64);
            ssq[nt]  += __shfl_xor(ssq[nt], 32, 64);
        }
        if (q == 0) {
            #pragma unroll
            for (int nt = 0; nt < 4; nt++) {
                atomicAdd(&gsums[colBase + nt * 16 + cl], ssum[nt]);
                atomicAdd(&gsqs[colBase + nt * 16 + cl], ssq[nt]);
            }
        }
    }
}

// ======== BN params ========
__global__ void bnparam_kernel(const float* __restrict__ sums, const float* __restrict__ sqs,
                               const float* __restrict__ gamma, const float* __restrict__ beta,
                               float* __restrict__ scale, float* __restrict__ shift,
                               int N, float invM)
{
    int c = blockIdx.x * blockDim.x + threadIdx.x;
    if (c < N) {
        float mean = sums[c] * invM;
        float var = sqs[c] * invM - mean * mean;
        float sc = gamma[c] * rsqrtf(var + BN_EPS);
        scale[c] = sc;
        shift[c] = beta[c] - mean * sc;
    }
}

// ======== BN + act, bf16 -> bf16 (x4 vector), input contiguous, output strided ========
__global__ __launch_bounds__(256) void bnact_bf16(
    const ushort* __restrict__ X, const float* __restrict__ scale, const float* __restrict__ shift,
    ushort* __restrict__ O, int total4, int logN, int outStride, float negSlope)
{
    int stride = gridDim.x * blockDim.x;
    int Nm1 = (1 << logN) - 1;
    for (int t = blockIdx.x * blockDim.x + threadIdx.x; t < total4; t += stride) {
        int idx = t * 4;
        int row = idx >> logN;
        int c = idx & Nm1;
        ushort4 v4 = *(const ushort4*)&X[idx];
        float4 sc = *(const float4*)&scale[c];
        float4 sh = *(const float4*)&shift[c];
        float a = bf2f(v4.x) * sc.x + sh.x; a = (a > 0.f) ? a : a * negSlope;
        float b = bf2f(v4.y) * sc.y + sh.y; b = (b > 0.f) ? b : b * negSlope;
        float d = bf2f(v4.z) * sc.z + sh.z; d = (d > 0.f) ? d : d * negSlope;
        float e = bf2f(v4.w) * sc.w + sh.w; e = (e > 0.f) ? e : e * negSlope;
        ushort4 o; o.x = f2bf(a); o.y = f2bf(b); o.z = f2bf(d); o.w = f2bf(e);
        *(ushort4*)&O[(long)row * outStride + c] = o;
    }
}

// ======== BN + act, fp32 in-place (final output) ========
__global__ __launch_bounds__(256) void bnact_f32(
    float* __restrict__ X, const float* __restrict__ scale, const float* __restrict__ shift,
    int total4, int logN, float negSlope)
{
    int stride = gridDim.x * blockDim.x;
    int Nm1 = (1 << logN) - 1;
    for (int t = blockIdx.x * blockDim.x + threadIdx.x; t < total4; t += stride) {
        int idx = t * 4;
        int c = idx & Nm1;
        float4 v = *(const float4*)&X[idx];
        float4 sc = *(const float4*)&scale[c];
        float4 sh = *(const float4*)&shift[c];
        float a = v.x * sc.x + sh.x; a = (a > 0.f) ? a : a * negSlope;
        float b = v.y * sc.y + sh.y; b = (b > 0.f) ? b : b * negSlope;
        float d = v.z * sc.z + sh.z; d = (d > 0.f) ? d : d * negSlope;
        float e = v.w * sc.w + sh.w; e = (e > 0.f) ? e : e * negSlope;
        *(float4*)&X[idx] = make_float4(a, b, d, e);
    }
}

// ======== column stats for final output (128 cols, register accum) ========
__global__ __launch_bounds__(256) void colstats128(
    const float* __restrict__ X, float* __restrict__ sums, float* __restrict__ sqs, int M)
{
    __shared__ float ss[128], sq[128];
    int tid = threadIdx.x;
    if (tid < 128) { ss[tid] = 0.f; sq[tid] = 0.f; }
    __syncthreads();
    int cg = tid & 31;
    int worker = (blockIdx.x << 3) | (tid >> 5);
    int totalW = gridDim.x << 3;
    float4 s4 = make_float4(0, 0, 0, 0), q4 = make_float4(0, 0, 0, 0);
    for (int r = worker; r < M; r += totalW) {
        float4 v = *(const float4*)&X[(long)r * 128 + cg * 4];
        s4.x += v.x; s4.y += v.y; s4.z += v.z; s4.w += v.w;
        q4.x += v.x * v.x; q4.y += v.y * v.y; q4.z += v.z * v.z; q4.w += v.w * v.w;
    }
    atomicAdd(&ss[cg * 4 + 0], s4.x); atomicAdd(&sq[cg * 4 + 0], q4.x);
    atomicAdd(&ss[cg * 4 + 1], s4.y); atomicAdd(&sq[cg * 4 + 1], q4.y);
    atomicAdd(&ss[cg * 4 + 2], s4.z); atomicAdd(&sq[cg * 4 + 2], q4.z);
    atomicAdd(&ss[cg * 4 + 3], s4.w); atomicAdd(&sq[cg * 4 + 3], q4.w);
    __syncthreads();
    if (tid < 128) { atomicAdd(&sums[tid], ss[tid]); atomicAdd(&sqs[tid], sq[tid]); }
}

// ======== converts ========
__global__ void convert_nodes(const float* __restrict__ X, ushort* __restrict__ O, int total4)
{
    int t = blockIdx.x * blockDim.x + threadIdx.x;
    if (t < total4) {
        float4 v = *(const float4*)&X[t * 4];
        ushort4 o; o.x = f2bf(v.x); o.y = f2bf(v.y); o.z = f2bf(v.z); o.w = f2bf(v.w);
        *(ushort4*)&O[t * 4] = o;
    }
}

__global__ void wt_all(const float* __restrict__ W0, const float* __restrict__ W1,
                       const float* __restrict__ W2, const float* __restrict__ W3,
                       const float* __restrict__ W4, const float* __restrict__ W5,
                       ushort* __restrict__ WT)
{
    int seg = blockIdx.y;
    const float* W; int logK, dstBase, stride, kOff;
    switch (seg) {
        case 0: W = W0; logK = 7; dstBase = 0;      stride = 128; kOff = 0;   break;
        case 1: W = W1; logK = 8; dstBase = 32768;  stride = 256; kOff = 0;   break;
        case 2: W = W2; logK = 7; dstBase = 65536;  stride = 256; kOff = 0;   break;
        case 3: W = W3; logK = 7; dstBase = 65536;  stride = 256; kOff = 128; break;
        case 4: W = W4; logK = 8; dstBase = 131072; stride = 256; kOff = 0;   break;
        default:W = W5; logK = 8; dstBase = 163840; stride = 256; kOff = 0;   break;
    }
    int t = blockIdx.x * blockDim.x + threadIdx.x;
    int N = 32768 >> logK;
    int k = t & ((1 << logK) - 1);
    int n = t >> logK;
    WT[(long)dstBase + (long)n * stride + kOff + k] = f2bf(W[(long)k * N + n]);
}

// ======== CSR build ========
__global__ void degcount_kernel(const int* __restrict__ dst, int* __restrict__ degi, int E)
{
    int i = blockIdx.x * blockDim.x + threadIdx.x;
    if (i < E) atomicAdd(&degi[dst[i]], 1);
}

__global__ __launch_bounds__(256) void scan_block_sums(const int* __restrict__ degi,
                                                       int* __restrict__ partial, int n)
{
    __shared__ int s[256];
    int i = blockIdx.x * 256 + threadIdx.x;
    s[threadIdx.x] = (i < n) ? degi[i] : 0;
    __syncthreads();
    for (int off = 128; off > 0; off >>= 1) {
        if (threadIdx.x < off) s[threadIdx.x] += s[threadIdx.x + off];
        __syncthreads();
    }
    if (threadIdx.x == 0) partial[blockIdx.x] = s[0];
}

__global__ __launch_bounds__(256) void scan_partials(int* __restrict__ partial, int nb)
{
    __shared__ int s[256];
    int v = (threadIdx.x < nb) ? partial[threadIdx.x] : 0;
    s[threadIdx.x] = v;
    __syncthreads();
    for (int off = 1; off < 256; off <<= 1) {
        int t = (threadIdx.x >= off) ? s[threadIdx.x - off] : 0;
        __syncthreads();
        s[threadIdx.x] += t;
        __syncthreads();
    }
    if (threadIdx.x < nb) partial[threadIdx.x] = s[threadIdx.x] - v;
}

__global__ __launch_bounds__(256) void scan_final(const int* __restrict__ degi,
                                                  const int* __restrict__ partial,
                                                  int* __restrict__ rowstart, int n)
{
    __shared__ int s[256];
    int i = blockIdx.x * 256 + threadIdx.x;
    int v = (i < n) ? degi[i] : 0;
    s[threadIdx.x] = v;
    __syncthreads();
    for (int off = 1; off < 256; off <<= 1) {
        int t = (threadIdx.x >= off) ? s[threadIdx.x - off] : 0;
        __syncthreads();
        s[threadIdx.x] += t;
        __syncthreads();
    }
    if (i < n) rowstart[i] = partial[blockIdx.x] + s[threadIdx.x] - v;
}

__global__ void fillcsr_kernel(const int* __restrict__ src, const int* __restrict__ dst,
                               const int* __restrict__ rowstart, int* __restrict__ cursor,
                               int* __restrict__ csr, int E)
{
    int i = blockIdx.x * blockDim.x + threadIdx.x;
    if (i < E) {
        int d = dst[i];
        int p = atomicAdd(&cursor[d], 1);
        csr[rowstart[d] + p] = src[i];
    }
}

// ======== gather mean (bf16 in/out), one wave per node, 128 cols, unroll-4 MLP ========
__global__ __launch_bounds__(256) void gather_bf(
    const ushort* __restrict__ X, const int* __restrict__ rowstart,
    const int* __restrict__ degi, const int* __restrict__ csr,
    ushort* __restrict__ O, int nN)
{
    int wv = (blockIdx.x * blockDim.x + threadIdx.x) >> 6;
    int lane = threadIdx.x & 63;
    if (wv >= nN) return;
    int start = rowstart[wv], d = degi[wv];
    float a0 = 0.f, a1 = 0.f;
    int col = lane * 2;
    int j = 0;
    for (; j + 4 <= d; j += 4) {
        int s0 = csr[start + j + 0];
        int s1 = csr[start + j + 1];
        int s2 = csr[start + j + 2];
        int s3 = csr[start + j + 3];
        unsigned p0 = *(const unsigned*)(X + (long)s0 * 256 + col);
        unsigned p1 = *(const unsigned*)(X + (long)s1 * 256 + col);
        unsigned p2 = *(const unsigned*)(X + (long)s2 * 256 + col);
        unsigned p3 = *(const unsigned*)(X + (long)s3 * 256 + col);
        a0 += bf2f((ushort)(p0 & 0xffff)) + bf2f((ushort)(p1 & 0xffff))
            + bf2f((ushort)(p2 & 0xffff)) + bf2f((ushort)(p3 & 0xffff));
        a1 += bf2f((ushort)(p0 >> 16)) + bf2f((ushort)(p1 >> 16))
            + bf2f((ushort)(p2 >> 16)) + bf2f((ushort)(p3 >> 16));
    }
    for (; j < d; j++) {
        int s0 = csr[start + j];
        unsigned p0 = *(const unsigned*)(X + (long)s0 * 256 + col);
        a0 += bf2f((ushort)(p0 & 0xffff));
        a1 += bf2f((ushort)(p0 >> 16));
    }
    float inv = 1.f / fmaxf((float)d, 1.f);
    unsigned o = (unsigned)f2bf(a0 * inv) | ((unsigned)f2bf(a1 * inv) << 16);
    *(unsigned*)(O + (long)wv * 256 + col) = o;
}

// ======== fused gather2: out = mean(Z[src, 0:128]) + Z[dst, 128:256], unroll-4 ========
__global__ __launch_bounds__(256) void gather_fuse(
    const ushort* __restrict__ Z, const int* __restrict__ rowstart,
    const int* __restrict__ degi, const int* __restrict__ csr,
    float* __restrict__ O, int nN)
{
    int wv = (blockIdx.x * blockDim.x + threadIdx.x) >> 6;
    int lane = threadIdx.x & 63;
    if (wv >= nN) return;
    int start = rowstart[wv], d = degi[wv];
    float a0 = 0.f, a1 = 0.f;
    int col = lane * 2;
    int j = 0;
    for (; j + 4 <= d; j += 4) {
        int s0 = csr[start + j + 0];
        int s1 = csr[start + j + 1];
        int s2 = csr[start + j + 2];
        int s3 = csr[start + j + 3];
        unsigned p0 = *(const unsigned*)(Z + (long)s0 * 256 + col);
        unsigned p1 = *(const unsigned*)(Z + (long)s1 * 256 + col);
        unsigned p2 = *(const unsigned*)(Z + (long)s2 * 256 + col);
        unsigned p3 = *(const unsigned*)(Z + (long)s3 * 256 + col);
        a0 += bf2f((ushort)(p0 & 0xffff)) + bf2f((ushort)(p1 & 0xffff))
            + bf2f((ushort)(p2 & 0xffff)) + bf2f((ushort)(p3 & 0xffff));
        a1 += bf2f((ushort)(p0 >> 16)) + bf2f((ushort)(p1 >> 16))
            + bf2f((ushort)(p2 >> 16)) + bf2f((ushort)(p3 >> 16));
    }
    for (; j < d; j++) {
        int s0 = csr[start + j];
        unsigned p0 = *(const unsigned*)(Z + (long)s0 * 256 + col);
        a0 += bf2f((ushort)(p0 & 0xffff));
        a1 += bf2f((ushort)(p0 >> 16));
    }
    float inv = 1.f / fmaxf((float)d, 1.f);
    unsigned sv = *(const unsigned*)(Z + (long)wv * 256 + 128 + col);
    float s0 = bf2f((ushort)(sv & 0xffff));
    float s1 = bf2f((ushort)(sv >> 16));
    *(float2*)(O + (long)wv * 128 + col) = make_float2(a0 * inv + s0, a1 * inv + s1);
}

extern "C" void kernel_launch(void* const* d_in, const int* in_sizes, int n_in,
                              void* d_out, int out_size, void* d_ws, size_t ws_size,
                              hipStream_t stream)
{
    const float* nodes = (const float*)d_in[0];
    const int*   src   = (const int*)d_in[1];
    const int*   dst   = (const int*)d_in[2];
    const float* Wf1   = (const float*)d_in[3];
    const float* gf1   = (const float*)d_in[5];
    const float* bef1  = (const float*)d_in[6];
    const float* Wf2   = (const float*)d_in[7];
    const float* gf2   = (const float*)d_in[9];
    const float* bef2  = (const float*)d_in[10];
    const float* Ws1   = (const float*)d_in[11];
    const float* Wn1   = (const float*)d_in[12];
    const float* gs1   = (const float*)d_in[14];
    const float* bs1   = (const float*)d_in[15];
    const float* Ws2   = (const float*)d_in[16];
    const float* Wn2   = (const float*)d_in[17];
    const float* gs2   = (const float*)d_in[19];
    const float* bs2   = (const float*)d_in[20];
    // pre-BN biases (bf1,bf2,b1,b2) cancel under BatchNorm -> skipped

    int nN = in_sizes[0] / DIN;   // 50000
    int nE = in_sizes[1];         // 600000
    float* out = (float*)d_out;
    int mStrips = nN / 16;        // 3125 (exact)

    // ---- workspace (identical layout to round-6 passing version) ----
    ushort* PRE = (ushort*)d_ws;                      // nN*256 bf16 pre-BN GEMM out
    ushort* BF1 = PRE + (size_t)nN * 256;             // nN*256 bf16 (Xn / X1 / h1)
    ushort* BF2 = BF1 + (size_t)nN * 256;             // nN*256 bf16 ([h|agg] / Z)
    float* stats = (float*)(BF2 + (size_t)nN * 256);  // 2048 floats, 4 layer-regions
    float* scale = stats + 2048;                      // 256
    float* shift = scale + 256;                       // 256
    ushort* WT   = (ushort*)(shift + 256);            // 196608 shorts
    int* degi     = (int*)(WT + 196608);              // nN
    int* cursor   = degi + nN;                        // nN (adjacent: one memset)
    int* rowstart = cursor + nN;                      // nN
    int* partial  = rowstart + nN;                    // 256
    int* csr      = partial + 256;                    // nE

    ushort* Wf1T = WT;
    ushort* Wf2T = WT + 32768;
    ushort* Wc1T = WT + 65536;
    ushort* Wc2T = WT + 131072;

    dim3 blk(256);
    auto cdiv = [](int a, int b) { return (a + b - 1) / b; };
    int nScanBlocks = cdiv(nN, 256);

    // ---- converts + zero-init ----
    convert_nodes<<<dim3(cdiv(nN * DIN / 4, 256)), blk, 0, stream>>>(nodes, BF1, nN * DIN / 4);
    wt_all<<<dim3(128, 6), blk, 0, stream>>>(Wf1, Wf2, Ws1, Wn1, Wn2, Ws2, WT);
    hipMemsetAsync(stats, 0, 2048 * sizeof(float), stream);
    hipMemsetAsync(degi, 0, 2 * (size_t)nN * sizeof(int), stream);

    // ---- CSR build ----
    degcount_kernel<<<dim3(cdiv(nE, 256)), blk, 0, stream>>>(dst, degi, nE);
    scan_block_sums<<<dim3(nScanBlocks), blk, 0, stream>>>(degi, partial, nN);
    scan_partials<<<dim3(1), blk, 0, stream>>>(partial, nScanBlocks);
    scan_final<<<dim3(nScanBlocks), blk, 0, stream>>>(degi, partial, rowstart, nN);
    fillcsr_kernel<<<dim3(cdiv(nE, 256)), blk, 0, stream>>>(src, dst, rowstart, cursor, csr, nE);

    // ---- FF1: PRE = Xn @ Wf1T (K=128, N=256, stats->L0) ; BN+ReLU -> BF1 ----
    gemm_wreg<4, 1><<<dim3(512), blk, 0, stream>>>(BF1, Wf1T, PRE, mStrips, 256, 128, 2, stats, stats + 256);
    bnparam_kernel<<<dim3(1), blk, 0, stream>>>(stats, stats + 256, gf1, bef1, scale, shift, 256, 1.0f / nN);
    bnact_bf16<<<dim3(2048), blk, 0, stream>>>(PRE, scale, shift, BF1, nN * 256 / 4, 8, 256, 0.0f);

    // ---- FF2: PRE = BF1 @ Wf2T (K=256, N=128, stats->L1) ; BN+ReLU -> BF2[:,0:128] ----
    gemm_wreg<8, 1><<<dim3(256), blk, 0, stream>>>(BF1, Wf2T, PRE, mStrips, 128, 256, 1, stats + 512, stats + 768);
    bnparam_kernel<<<dim3(1), blk, 0, stream>>>(stats + 512, stats + 768, gf2, bef2, scale, shift, 128, 1.0f / nN);
    bnact_bf16<<<dim3(2048), blk, 0, stream>>>(PRE, scale, shift, BF2, nN * 128 / 4, 7, 256, 0.0f);

    // ---- gather1: BF2[:,128:256] = mean-gather(BF2[:,0:128]) ----
    gather_bf<<<dim3(cdiv(nN * 64, 256)), blk, 0, stream>>>(BF2, rowstart, degi, csr, BF2 + 128, nN);

    // ---- SAGE1: PRE = [h|agg] @ [Ws1;Wn1] (K=256, N=256, stats->L2) ; BN+LReLU -> BF1 (h1) ----
    gemm_wreg<8, 1><<<dim3(512), blk, 0, stream>>>(BF2, Wc1T, PRE, mStrips, 256, 256, 2, stats + 1024, stats + 1280);
    bnparam_kernel<<<dim3(1), blk, 0, stream>>>(stats + 1024, stats + 1280, gs1, bs1, scale, shift, 256, 1.0f / nN);
    bnact_bf16<<<dim3(2048), blk, 0, stream>>>(PRE, scale, shift, BF1, nN * 256 / 4, 8, 256, 0.01f);

    // ---- SAGE2: BF2 = h1 @ [Wn2|Ws2] (K=256, N=256, no stats) ; gather_fuse -> out(fp32) ----
    gemm_wreg<8, 0><<<dim3(512), blk, 0, stream>>>(BF1, Wc2T, BF2, mStrips, 256, 256, 2, nullptr, nullptr);
    gather_fuse<<<dim3(cdiv(nN * 64, 256)), blk, 0, stream>>>(BF2, rowstart, degi, csr, out, nN);

    // ---- final: colstats -> BN params -> BN+LReLU on out ----
    colstats128<<<dim3(120), blk, 0, stream>>>(out, stats + 1536, stats + 1792, nN);
    bnparam_kernel<<<dim3(1), blk, 0, stream>>>(stats + 1536, stats + 1792, gs2, bs2, scale, shift, 128, 1.0f / nN);
    bnact_f32<<<dim3(2048), blk, 0, stream>>>(out, scale, shift, nN * 128 / 4, 7, 0.01f);
}